// Round 12
// baseline (161.069 us; speedup 1.0000x reference)
//
#include <hip/hip_runtime.h>

#define BB 8
#define C 64
#define HW 4096

typedef __attribute__((ext_vector_type(8))) __bf16 bf16x8;
typedef __attribute__((ext_vector_type(16))) float f32x16;
typedef unsigned int uint;
typedef unsigned short ushort;

__device__ __forceinline__ ushort bfb(float f) {
  return __builtin_bit_cast(ushort, (__bf16)f);
}
__device__ __forceinline__ uint pk2(float a, float b) {
  return (uint)bfb(a) | ((uint)bfb(b) << 16);
}
__device__ __forceinline__ uint cvtpk(float a, float b) {
  uint r;
  asm("v_cvt_pk_bf16_f32 %0, %1, %2" : "=v"(r) : "v"(a), "v"(b));
  return r;
}
__device__ __forceinline__ f32x16 mfma_bf16(bf16x8 a, bf16x8 b, f32x16 c) {
  return __builtin_amdgcn_mfma_f32_32x32x16_bf16(a, b, c, 0, 0, 0);
}

// ---------------- K1: [fold | gram] ----------------
// fold: wall A/B fragments for {q*log2e, k, wvp}. gram: per-wave partial
// G = X X^T (split-x h+l bf16 MFMA), plain stores into Gp (no zero-init needed).
__global__ __launch_bounds__(128) void gram_fold_kernel(const float* __restrict__ x,
                                                        float* __restrict__ Gp,
                                                        const float* __restrict__ w_bn,
                                                        const float* __restrict__ w_q,
                                                        const float* __restrict__ w_k,
                                                        const float* __restrict__ w_v,
                                                        char* __restrict__ wall) {
  const int bxx = blockIdx.x;
  const int t = threadIdx.x;
  if (bxx < 8) {
    // ---- fold ----
    const int slot = bxx * 2 + (t >> 6);   // ot*4 + kc
    const int ot = slot >> 2, kc = slot & 3;
    const int l = t & 63, lo5 = l & 31, hi = l >> 5;
    float v[8];
    if (ot == 0) {
#pragma unroll
      for (int j = 0; j < 8; ++j)
        v[j] = 1.44269504088896f * w_q[lo5 * 64 + kc * 16 + hi * 8 + j];
    } else if (ot == 1) {
#pragma unroll
      for (int j = 0; j < 8; ++j) v[j] = w_k[lo5 * 64 + kc * 16 + hi * 8 + j];
    } else {
      int c = (ot - 2) * 32 + lo5;
#pragma unroll
      for (int j = 0; j < 8; ++j) {
        int d = kc * 16 + hi * 8 + j;
        float acc = 0.f;
        for (int e = 0; e < 64; ++e) acc += w_bn[c * 128 + 64 + e] * w_v[e * 64 + d];
        v[j] = acc;
      }
    }
    uint4 w;
    w.x = pk2(v[0], v[1]); w.y = pk2(v[2], v[3]);
    w.z = pk2(v[4], v[5]); w.w = pk2(v[6], v[7]);
    *(uint4*)(wall + slot * 1024 + l * 16) = w;
    return;
  }
  // ---- gram ----
  const int bx = bxx - 8;
  const int b = bx >> 5, ch = bx & 31;
  const int wv = t >> 6, l = t & 63, lo5 = l & 31, hi = l >> 5;
  const int n0 = ch * 128 + wv * 64;
  const float* xb = x + (size_t)b * C * HW;
  f32x16 fz;
#pragma unroll
  for (int r = 0; r < 16; ++r) fz[r] = 0.f;
  f32x16 a00 = fz, a01 = fz, a10 = fz, a11 = fz;
#pragma unroll 1
  for (int kc = 0; kc < 4; ++kc) {
    int nb = n0 + kc * 16 + hi * 8;
    const float4* p0 = (const float4*)(xb + (size_t)lo5 * HW + nb);
    const float4* p1 = (const float4*)(xb + (size_t)(32 + lo5) * HW + nb);
    float v0[8], v1[8];
    {
      float4 a = p0[0], bq = p0[1];
      v0[0] = a.x; v0[1] = a.y; v0[2] = a.z; v0[3] = a.w;
      v0[4] = bq.x; v0[5] = bq.y; v0[6] = bq.z; v0[7] = bq.w;
      float4 c = p1[0], d = p1[1];
      v1[0] = c.x; v1[1] = c.y; v1[2] = c.z; v1[3] = c.w;
      v1[4] = d.x; v1[5] = d.y; v1[6] = d.z; v1[7] = d.w;
    }
    uint4 uh0, ul0, uh1, ul1;
    {
      float h[8], e[8];
#pragma unroll
      for (int j = 0; j < 8; ++j) { h[j] = (float)(__bf16)v0[j]; e[j] = v0[j] - h[j]; }
      uh0.x = pk2(h[0], h[1]); uh0.y = pk2(h[2], h[3]); uh0.z = pk2(h[4], h[5]); uh0.w = pk2(h[6], h[7]);
      ul0.x = cvtpk(e[0], e[1]); ul0.y = cvtpk(e[2], e[3]); ul0.z = cvtpk(e[4], e[5]); ul0.w = cvtpk(e[6], e[7]);
#pragma unroll
      for (int j = 0; j < 8; ++j) { h[j] = (float)(__bf16)v1[j]; e[j] = v1[j] - h[j]; }
      uh1.x = pk2(h[0], h[1]); uh1.y = pk2(h[2], h[3]); uh1.z = pk2(h[4], h[5]); uh1.w = pk2(h[6], h[7]);
      ul1.x = cvtpk(e[0], e[1]); ul1.y = cvtpk(e[2], e[3]); ul1.z = cvtpk(e[4], e[5]); ul1.w = cvtpk(e[6], e[7]);
    }
    bf16x8 f0h = __builtin_bit_cast(bf16x8, uh0);
    bf16x8 f0l = __builtin_bit_cast(bf16x8, ul0);
    bf16x8 f1h = __builtin_bit_cast(bf16x8, uh1);
    bf16x8 f1l = __builtin_bit_cast(bf16x8, ul1);
    a00 = mfma_bf16(f0h, f0h, a00); a00 = mfma_bf16(f0h, f0l, a00); a00 = mfma_bf16(f0l, f0h, a00);
    a01 = mfma_bf16(f0h, f1h, a01); a01 = mfma_bf16(f0h, f1l, a01); a01 = mfma_bf16(f0l, f1h, a01);
    a10 = mfma_bf16(f1h, f0h, a10); a10 = mfma_bf16(f1h, f0l, a10); a10 = mfma_bf16(f1l, f0h, a10);
    a11 = mfma_bf16(f1h, f1h, a11); a11 = mfma_bf16(f1h, f1l, a11); a11 = mfma_bf16(f1l, f1h, a11);
  }
  // partial index within b: ch*2+wv  (64 partials per b)
  float* g = Gp + ((size_t)(b * 64 + ch * 2 + wv)) * 4096;
#pragma unroll
  for (int r = 0; r < 16; ++r) {
    int row = (r & 3) + 8 * (r >> 2) + 4 * hi;
    g[row * 64 + lo5] = a00[r];
    g[row * 64 + 32 + lo5] = a01[r];
    g[(32 + row) * 64 + lo5] = a10[r];
    g[(32 + row) * 64 + 32 + lo5] = a11[r];
  }
}

// ---------------- cam body (256 threads, 16 KB LDS): reduce Gp, E = Wc G Wc^T, softmax, M1 ----------------
__device__ __forceinline__ void cam_body(const float* __restrict__ Gp,
                                         const float* __restrict__ w_cam,
                                         const float* __restrict__ w_bn,
                                         float* __restrict__ m1,
                                         int b, float* buf) {
  const int t = threadIdx.x;
#pragma unroll
  for (int i = 0; i < 16; ++i) {
    int idx = t + i * 256;
    float s = 0.f;
    for (int s32 = 0; s32 < 64; ++s32)
      s += Gp[((size_t)(b * 64 + s32)) * 4096 + idx];
    buf[idx] = s;
  }
  __syncthreads();
  const int lane = t & 63, rg = (t >> 6) * 16;
  float acc[16];
#pragma unroll
  for (int r = 0; r < 16; ++r) acc[r] = 0.f;
  for (int c = 0; c < 64; ++c) {
    float g = buf[c * 64 + lane];
#pragma unroll
    for (int r = 0; r < 16; ++r) acc[r] += w_cam[(rg + r) * 64 + c] * g;
  }
  __syncthreads();
#pragma unroll
  for (int r = 0; r < 16; ++r) buf[(rg + r) * 64 + lane] = acc[r];   // T1
  __syncthreads();
#pragma unroll
  for (int r = 0; r < 16; ++r) acc[r] = 0.f;
  for (int d = 0; d < 64; ++d) {
    float wl = w_cam[lane * 64 + d];
#pragma unroll
    for (int r = 0; r < 16; ++r) acc[r] += buf[(rg + r) * 64 + d] * wl;
  }
  __syncthreads();
#pragma unroll
  for (int r = 0; r < 16; ++r) buf[(rg + r) * 64 + lane] = acc[r];   // E
  __syncthreads();
  {
    int row = t >> 2, c0 = (t & 3) * 16;
    float v[16];
    float mx = -1e30f;
#pragma unroll
    for (int j = 0; j < 16; ++j) { v[j] = buf[row * 64 + c0 + j]; mx = fmaxf(mx, v[j]); }
    mx = fmaxf(mx, __shfl_xor(mx, 1));
    mx = fmaxf(mx, __shfl_xor(mx, 2));
    float s = 0.f;
#pragma unroll
    for (int j = 0; j < 16; ++j) { v[j] = __expf(v[j] - mx); s += v[j]; }
    s += __shfl_xor(s, 1);
    s += __shfl_xor(s, 2);
    float inv = 1.f / s;
#pragma unroll
    for (int j = 0; j < 16; ++j) buf[row * 64 + c0 + j] = v[j] * inv;  // attn
  }
  __syncthreads();
  float a2[16];
#pragma unroll
  for (int dd = 0; dd < 16; ++dd) a2[dd] = 0.f;
  for (int r = 0; r < 64; ++r) {
    float wv = w_bn[lane * 128 + r];
#pragma unroll
    for (int dd = 0; dd < 16; ++dd) a2[dd] += wv * buf[r * 64 + rg + dd];
  }
  float* mb = m1 + (size_t)b * 4096;
#pragma unroll
  for (int dd = 0; dd < 16; ++dd) mb[(rg + dd) * 64 + lane] = a2[dd];
}

// ---------------- K2: [cam | prep]; prep: q/k/vp via MFMA, fa-exact fragment layouts ----------------
__global__ __launch_bounds__(256) void prep_cam_kernel(const float* __restrict__ x,
                                                       const char* __restrict__ wall,
                                                       char* __restrict__ qd2,
                                                       char* __restrict__ kd2,
                                                       char* __restrict__ vpd2,
                                                       const float* __restrict__ Gp,
                                                       const float* __restrict__ w_cam,
                                                       const float* __restrict__ w_bn,
                                                       float* __restrict__ m1) {
  __shared__ float buf[4096];
  const int bxx = blockIdx.x;
  if (bxx < 8) {
    cam_body(Gp, w_cam, w_bn, m1, bxx, buf);
    return;
  }
  const int bx = bxx - 8;
  const int b = bx >> 5, nt2 = bx & 31;
  const int t = threadIdx.x;
  const int wv = t >> 6, l = t & 63, lo5 = l & 31, hi = l >> 5;
  const int chunk = nt2 * 4 + wv;        // 0..127, 32-wide n chunk
  const int n0 = chunk * 32;
  const int tt = chunk >> 1;
  const int n = n0 + lo5;
  const float* xb = x + (size_t)b * C * HW;

  f32x16 fz;
#pragma unroll
  for (int r = 0; r < 16; ++r) fz[r] = 0.f;

  bf16x8 xf[4];
#pragma unroll
  for (int kc = 0; kc < 4; ++kc) {
    float xv[8];
#pragma unroll
    for (int j = 0; j < 8; ++j)
      xv[j] = xb[(size_t)(kc * 16 + hi * 8 + j) * HW + n];
    uint4 u;
    u.x = cvtpk(xv[0], xv[1]); u.y = cvtpk(xv[2], xv[3]);
    u.z = cvtpk(xv[4], xv[5]); u.w = cvtpk(xv[6], xv[7]);
    xf[kc] = __builtin_bit_cast(bf16x8, u);
  }

#pragma unroll
  for (int ot = 0; ot < 4; ++ot) {
    f32x16 acc = fz;
#pragma unroll
    for (int kc = 0; kc < 4; ++kc) {
      bf16x8 wf = *(const bf16x8*)(wall + ((ot << 2) | kc) * 1024 + l * 16);
      acc = (ot < 2) ? mfma_bf16(wf, xf[kc], acc)    // D[col=n][row=out]
                     : mfma_bf16(xf[kc], wf, acc);   // D[col=c][row=m]
    }
    uint wlo[8], whi[8];
#pragma unroll
    for (int i2 = 0; i2 < 8; ++i2) {
      uint w = cvtpk(acc[2 * i2], acc[2 * i2 + 1]);
      uint p = __shfl_xor(w, 32);
      wlo[i2] = hi ? p : w;
      whi[i2] = hi ? w : p;
    }
    uint4 u40, u41;
    u40.x = hi ? wlo[4] : wlo[0];
    u40.y = hi ? wlo[5] : wlo[1];
    u40.z = hi ? whi[4] : whi[0];
    u40.w = hi ? whi[5] : whi[1];
    u41.x = hi ? wlo[6] : wlo[2];
    u41.y = hi ? wlo[7] : wlo[3];
    u41.z = hi ? whi[6] : whi[2];
    u41.w = hi ? whi[7] : whi[3];
    const int e0 = hi * 2;
    if (ot == 0) {
      char* p = qd2 + ((size_t)b * HW + n) * 64;
      *(uint4*)(p + e0 * 16) = u40;
      *(uint4*)(p + (e0 + 1) * 16) = u41;
    } else if (ot == 1) {
      char* p = kd2 + ((size_t)(b * 64 + tt)) * 4096 + (chunk & 1) * 2048 + (n & 31) * 16;
      *(uint4*)(p + e0 * 512) = u40;
      *(uint4*)(p + (e0 + 1) * 512) = u41;
    } else {
      int c = ((ot - 2) << 5) + lo5;
      int oct0 = (chunk & 1) * 4;
      char* p = vpd2 + ((size_t)(b * 64 + tt)) * 8192 + (c >> 5) * 4096 + (c & 31) * 16;
      *(uint4*)(p + (oct0 + e0) * 512) = u40;
      *(uint4*)(p + (oct0 + e0 + 1) * 512) = u41;
    }
  }
}

// ---------------- SAM flash attention: direct global->reg fragments, no LDS/barriers ----------------
__global__ __launch_bounds__(256) void fa_kernel(const char* __restrict__ qd2,
                                                 const char* __restrict__ kd2,
                                                 const char* __restrict__ vpd2,
                                                 char* __restrict__ op,
                                                 float* __restrict__ lp) {
  const int t = threadIdx.x;
  const int l = t & 63, lo5 = l & 31, hi = l >> 5;
  const int wv = t >> 6;
  const int bx = blockIdx.x;
  const int g = (bx & 7) | ((bx >> 8) << 3);   // XCD-aligned: group g lives on XCD g&7
  const int qt = (bx >> 3) & 31;
  const int b = g >> 2, kvs = g & 3;
  const int nq = qt * 128 + wv * 32 + lo5;

  const char* qb = qd2 + ((size_t)b * HW + nq) * 64;
  bf16x8 qf0 = *(const bf16x8*)(qb + hi * 16);
  bf16x8 qf1 = *(const bf16x8*)(qb + 32 + hi * 16);

  f32x16 fz;
#pragma unroll
  for (int r = 0; r < 16; ++r) fz[r] = 0.f;
  f32x16 o0 = fz, o1 = fz;
  float lrun = 0.f;

  const char* kbase = kd2 + ((size_t)(b * 64 + kvs * 16)) * 4096 + l * 16;
  const char* vbase = vpd2 + ((size_t)(b * 64 + kvs * 16)) * 8192 + l * 16;

  bf16x8 kf0 = *(const bf16x8*)(kbase);
  bf16x8 kf1 = *(const bf16x8*)(kbase + 1024);
  bf16x8 kf2 = *(const bf16x8*)(kbase + 2048);
  bf16x8 kf3 = *(const bf16x8*)(kbase + 3072);

#pragma unroll 1
  for (int i = 0; i < 16; ++i) {
    bf16x8 kn0, kn1, kn2, kn3;
    if (i < 15) {
      const char* kn = kbase + (size_t)(i + 1) * 4096;
      kn0 = *(const bf16x8*)(kn);
      kn1 = *(const bf16x8*)(kn + 1024);
      kn2 = *(const bf16x8*)(kn + 2048);
      kn3 = *(const bf16x8*)(kn + 3072);
    }
    const char* vb = vbase + (size_t)i * 8192;
    bf16x8 vfa[4], vfb[4];
#pragma unroll
    for (int ks = 0; ks < 4; ++ks) {
      vfa[ks] = *(const bf16x8*)(vb + ks * 1024);
      vfb[ks] = *(const bf16x8*)(vb + 4096 + ks * 1024);
    }
    f32x16 s0 = mfma_bf16(kf0, qf0, fz);
    s0 = mfma_bf16(kf1, qf1, s0);
    f32x16 s1 = mfma_bf16(kf2, qf0, fz);
    s1 = mfma_bf16(kf3, qf1, s1);
    float ps = 0.f;
#pragma unroll
    for (int r = 0; r < 16; ++r) {
      s0[r] = __builtin_amdgcn_exp2f(s0[r]);
      ps += s0[r];
    }
#pragma unroll
    for (int r = 0; r < 16; ++r) {
      s1[r] = __builtin_amdgcn_exp2f(s1[r]);
      ps += s1[r];
    }
    lrun += ps;                    // lane-local; cross-half merge once at end
#pragma unroll
    for (int ks = 0; ks < 4; ++ks) {
      const f32x16& pm = (ks < 2) ? s0 : s1;
      const int rb = (ks & 1) * 8;
      uint w0 = cvtpk(pm[rb + 0], pm[rb + 1]);
      uint w1 = cvtpk(pm[rb + 2], pm[rb + 3]);
      uint w2 = cvtpk(pm[rb + 4], pm[rb + 5]);
      uint w3 = cvtpk(pm[rb + 6], pm[rb + 7]);
      uint x0 = __shfl_xor(w0, 32);
      uint x1 = __shfl_xor(w1, 32);
      uint x2 = __shfl_xor(w2, 32);
      uint x3 = __shfl_xor(w3, 32);
      uint4 fw;
      fw.x = hi ? x2 : w0;
      fw.y = hi ? x3 : w1;
      fw.z = hi ? w2 : x0;
      fw.w = hi ? w3 : x1;
      bf16x8 pf = __builtin_bit_cast(bf16x8, fw);
      o0 = mfma_bf16(vfa[ks], pf, o0);
      o1 = mfma_bf16(vfb[ks], pf, o1);
    }
    kf0 = kn0; kf1 = kn1; kf2 = kn2; kf3 = kn3;
  }
  lrun += __shfl_xor(lrun, 32);

  ushort* opu = (ushort*)op;
  const size_t obase = ((size_t)(b * 64) * 4 + kvs) * HW + nq;
#pragma unroll
  for (int r = 0; r < 16; ++r) {
    int c0 = (r & 3) + 8 * (r >> 2) + 4 * hi;
    opu[obase + (size_t)c0 * 4 * HW] = bfb(o0[r]);
    opu[obase + (size_t)(c0 + 32) * 4 * HW] = bfb(o1[r]);
  }
  if (hi == 0) lp[(size_t)(kvs * 8 + b) * HW + nq] = lrun;
}

// ---------------- epilogue: out = x + M1@x + merge(op)/merge(l) ----------------
__global__ __launch_bounds__(256) void final_kernel(const float* __restrict__ x,
                                                    const float* __restrict__ m1,
                                                    const char* __restrict__ op,
                                                    const float* __restrict__ lp,
                                                    float* __restrict__ outp) {
  __shared__ __align__(16) float xt[4096];
  __shared__ __align__(16) float ms[4096];
  const int b = blockIdx.y, tt = blockIdx.x, t = threadIdx.x;
  const float4* xg = (const float4*)(x + (size_t)b * C * HW);
  float4* xt4 = (float4*)xt;
#pragma unroll
  for (int i = 0; i < 4; ++i) {
    int idx = t + i * 256;
    int c = idx >> 4, ng = idx & 15;
    xt4[c * 16 + (ng ^ (c & 15))] = xg[c * 1024 + tt * 16 + ng];
  }
  float4* ms4 = (float4*)ms;
  const float4* mg = (const float4*)(m1 + (size_t)b * 4096);
#pragma unroll
  for (int i = 0; i < 4; ++i) ms4[t + i * 256] = mg[t + i * 256];
  __syncthreads();
  const int n = t & 63, sub = t >> 6;
  const int gn = tt * 64 + n;
  float xr[64];
#pragma unroll
  for (int c = 0; c < 64; ++c)
    xr[c] = xt[c * 64 + (((n >> 2) ^ (c & 15)) << 2) + (n & 3)];
  float lsum = 0.f;
#pragma unroll
  for (int kvs = 0; kvs < 4; ++kvs) lsum += lp[(size_t)(kvs * 8 + b) * HW + gn];
  float linv = 1.f / lsum;
  const ushort* opu = (const ushort*)op;
  float acc[16];
#pragma unroll
  for (int ci = 0; ci < 16; ++ci) {
    int c = sub * 16 + ci;
    float osum = 0.f;
#pragma unroll
    for (int kvs = 0; kvs < 4; ++kvs) {
      ushort u = opu[((size_t)(b * 64 + c) * 4 + kvs) * HW + gn];
      osum += __builtin_bit_cast(float, (uint)u << 16);
    }
    acc[ci] = xr[c] + osum * linv;
  }
  for (int d = 0; d < 64; ++d) {
    float xv = xr[d];
    const float4* mr = (const float4*)(ms + d * 64 + sub * 16);
#pragma unroll
    for (int c4 = 0; c4 < 4; ++c4) {
      float4 mv = mr[c4];
      acc[c4 * 4 + 0] += mv.x * xv;
      acc[c4 * 4 + 1] += mv.y * xv;
      acc[c4 * 4 + 2] += mv.z * xv;
      acc[c4 * 4 + 3] += mv.w * xv;
    }
  }
  float* ob = outp + (size_t)b * C * HW + gn;
#pragma unroll
  for (int ci = 0; ci < 16; ++ci)
    ob[(size_t)(sub * 16 + ci) * HW] = acc[ci];
}

extern "C" void kernel_launch(void* const* d_in, const int* in_sizes, int n_in,
                              void* d_out, int out_size, void* d_ws, size_t ws_size,
                              hipStream_t stream) {
  const float* x     = (const float*)d_in[0];
  const float* w_cam = (const float*)d_in[1];
  const float* w_q   = (const float*)d_in[2];
  const float* w_k   = (const float*)d_in[3];
  const float* w_v   = (const float*)d_in[4];
  const float* w_bn  = (const float*)d_in[5];
  float* out = (float*)d_out;
  char* wsb = (char*)d_ws;

  // workspace layout (bytes) — total ~24.7 MB
  char*  wall = wsb;                               // 16 KB  wall fragments
  float* m1   = (float*)(wsb + 16384);             // 128 KB
  char*  qd2  = wsb + 147456;                      // 2 MB
  char*  kd2  = qd2 + 2097152;                     // 2 MB
  char*  vpd2 = kd2 + 2097152;                     // 4 MB
  float* lp   = (float*)(vpd2 + 4194304);          // 512 KB
  char*  op   = (char*)lp + 524288;                // 16 MB; Gp aliases first 8 MB
  float* Gp   = (float*)op;                        // 512 partials x 16 KB = 8 MB
  // alias safety: gram_fold writes Gp; prep_cam::cam reads Gp -> m1; fa then
  // overwrites the same bytes as op (stream-ordered after prep_cam); final reads op.

  gram_fold_kernel<<<264, 128, 0, stream>>>(x, Gp, w_bn, w_q, w_k, w_v, wall);
  prep_cam_kernel<<<264, 256, 0, stream>>>(x, wall, qd2, kd2, vpd2, Gp, w_cam, w_bn, m1);
  fa_kernel<<<1024, 256, 0, stream>>>(qd2, kd2, vpd2, op, lp);
  final_kernel<<<dim3(64, BB), 256, 0, stream>>>(x, m1, op, lp, out);
}

// Round 13
// 135.605 us; speedup vs baseline: 1.1878x; 1.1878x over previous
//
#include <hip/hip_runtime.h>

#define BB 8
#define C 64
#define HW 4096

typedef __attribute__((ext_vector_type(8))) __bf16 bf16x8;
typedef __attribute__((ext_vector_type(16))) float f32x16;
typedef unsigned int uint;
typedef unsigned short ushort;

__device__ __forceinline__ ushort bfb(float f) {
  return __builtin_bit_cast(ushort, (__bf16)f);
}
__device__ __forceinline__ uint pk2(float a, float b) {
  return (uint)bfb(a) | ((uint)bfb(b) << 16);
}
__device__ __forceinline__ uint cvtpk(float a, float b) {
  uint r;
  asm("v_cvt_pk_bf16_f32 %0, %1, %2" : "=v"(r) : "v"(a), "v"(b));
  return r;
}
__device__ __forceinline__ f32x16 mfma_bf16(bf16x8 a, bf16x8 b, f32x16 c) {
  return __builtin_amdgcn_mfma_f32_32x32x16_bf16(a, b, c, 0, 0, 0);
}

// ---------------- K1: [fold | gram] ----------------
// block 0: fold (16 slots x 64 lanes). blocks 1..8: gram, one block per b:
// 16 waves each compute a K=256 slice of G = X X^T (split-x h+l bf16 MFMA),
// reduced in-block via 4 LDS slots (store round + 3 add rounds), plain-stored
// to G. No memset, no atomics, no cross-kernel partials.
__global__ __launch_bounds__(1024) void gram_fold_kernel(const float* __restrict__ x,
                                                         float* __restrict__ G,
                                                         const float* __restrict__ w_bn,
                                                         const float* __restrict__ w_q,
                                                         const float* __restrict__ w_k,
                                                         const float* __restrict__ w_v,
                                                         char* __restrict__ wall) {
  __shared__ float slots[4][4096];   // 64 KB
  const int bxx = blockIdx.x;
  const int t = threadIdx.x;
  if (bxx == 0) {
    // ---- fold: slot = t>>6 ----
    const int slot = t >> 6;           // ot*4 + kc
    const int ot = slot >> 2, kc = slot & 3;
    const int l = t & 63, lo5 = l & 31, hi = l >> 5;
    float v[8];
    if (ot == 0) {
#pragma unroll
      for (int j = 0; j < 8; ++j)
        v[j] = 1.44269504088896f * w_q[lo5 * 64 + kc * 16 + hi * 8 + j];
    } else if (ot == 1) {
#pragma unroll
      for (int j = 0; j < 8; ++j) v[j] = w_k[lo5 * 64 + kc * 16 + hi * 8 + j];
    } else {
      int c = (ot - 2) * 32 + lo5;
#pragma unroll
      for (int j = 0; j < 8; ++j) {
        int d = kc * 16 + hi * 8 + j;
        float acc = 0.f;
        for (int e = 0; e < 64; ++e) acc += w_bn[c * 128 + 64 + e] * w_v[e * 64 + d];
        v[j] = acc;
      }
    }
    uint4 w;
    w.x = pk2(v[0], v[1]); w.y = pk2(v[2], v[3]);
    w.z = pk2(v[4], v[5]); w.w = pk2(v[6], v[7]);
    *(uint4*)(wall + slot * 1024 + l * 16) = w;
    return;
  }
  // ---- gram: one block per b, wave w covers K in [w*256, w*256+256) ----
  const int b = bxx - 1;
  const int w = t >> 6, l = t & 63, lo5 = l & 31, hi = l >> 5;
  const float* xb = x + (size_t)b * C * HW;
  f32x16 fz;
#pragma unroll
  for (int r = 0; r < 16; ++r) fz[r] = 0.f;
  f32x16 a00 = fz, a01 = fz, a10 = fz, a11 = fz;
  const int k0 = w * 256;
#pragma unroll 1
  for (int kc = 0; kc < 16; ++kc) {
    int nb = k0 + kc * 16 + hi * 8;
    const float4* p0 = (const float4*)(xb + (size_t)lo5 * HW + nb);
    const float4* p1 = (const float4*)(xb + (size_t)(32 + lo5) * HW + nb);
    float v0[8], v1[8];
    {
      float4 a = p0[0], bq = p0[1];
      v0[0] = a.x; v0[1] = a.y; v0[2] = a.z; v0[3] = a.w;
      v0[4] = bq.x; v0[5] = bq.y; v0[6] = bq.z; v0[7] = bq.w;
      float4 c = p1[0], d = p1[1];
      v1[0] = c.x; v1[1] = c.y; v1[2] = c.z; v1[3] = c.w;
      v1[4] = d.x; v1[5] = d.y; v1[6] = d.z; v1[7] = d.w;
    }
    uint4 uh0, ul0, uh1, ul1;
    {
      float h[8], e[8];
#pragma unroll
      for (int j = 0; j < 8; ++j) { h[j] = (float)(__bf16)v0[j]; e[j] = v0[j] - h[j]; }
      uh0.x = pk2(h[0], h[1]); uh0.y = pk2(h[2], h[3]); uh0.z = pk2(h[4], h[5]); uh0.w = pk2(h[6], h[7]);
      ul0.x = cvtpk(e[0], e[1]); ul0.y = cvtpk(e[2], e[3]); ul0.z = cvtpk(e[4], e[5]); ul0.w = cvtpk(e[6], e[7]);
#pragma unroll
      for (int j = 0; j < 8; ++j) { h[j] = (float)(__bf16)v1[j]; e[j] = v1[j] - h[j]; }
      uh1.x = pk2(h[0], h[1]); uh1.y = pk2(h[2], h[3]); uh1.z = pk2(h[4], h[5]); uh1.w = pk2(h[6], h[7]);
      ul1.x = cvtpk(e[0], e[1]); ul1.y = cvtpk(e[2], e[3]); ul1.z = cvtpk(e[4], e[5]); ul1.w = cvtpk(e[6], e[7]);
    }
    bf16x8 f0h = __builtin_bit_cast(bf16x8, uh0);
    bf16x8 f0l = __builtin_bit_cast(bf16x8, ul0);
    bf16x8 f1h = __builtin_bit_cast(bf16x8, uh1);
    bf16x8 f1l = __builtin_bit_cast(bf16x8, ul1);
    a00 = mfma_bf16(f0h, f0h, a00); a00 = mfma_bf16(f0h, f0l, a00); a00 = mfma_bf16(f0l, f0h, a00);
    a01 = mfma_bf16(f0h, f1h, a01); a01 = mfma_bf16(f0h, f1l, a01); a01 = mfma_bf16(f0l, f1h, a01);
    a10 = mfma_bf16(f1h, f0h, a10); a10 = mfma_bf16(f1h, f0l, a10); a10 = mfma_bf16(f1l, f0h, a10);
    a11 = mfma_bf16(f1h, f1h, a11); a11 = mfma_bf16(f1h, f1l, a11); a11 = mfma_bf16(f1l, f1h, a11);
  }
  const int sl = w & 3, rnd = w >> 2;
  if (rnd == 0) {
#pragma unroll
    for (int r = 0; r < 16; ++r) {
      int row = (r & 3) + 8 * (r >> 2) + 4 * hi;
      slots[sl][row * 64 + lo5] = a00[r];
      slots[sl][row * 64 + 32 + lo5] = a01[r];
      slots[sl][(32 + row) * 64 + lo5] = a10[r];
      slots[sl][(32 + row) * 64 + 32 + lo5] = a11[r];
    }
  }
  __syncthreads();
#pragma unroll 1
  for (int R = 1; R < 4; ++R) {
    if (rnd == R) {
#pragma unroll
      for (int r = 0; r < 16; ++r) {
        int row = (r & 3) + 8 * (r >> 2) + 4 * hi;
        slots[sl][row * 64 + lo5] += a00[r];
        slots[sl][row * 64 + 32 + lo5] += a01[r];
        slots[sl][(32 + row) * 64 + lo5] += a10[r];
        slots[sl][(32 + row) * 64 + 32 + lo5] += a11[r];
      }
    }
    __syncthreads();
  }
  float* g = G + (size_t)b * 4096;
#pragma unroll
  for (int i = 0; i < 4; ++i) {
    int idx = t + i * 1024;
    g[idx] = slots[0][idx] + slots[1][idx] + slots[2][idx] + slots[3][idx];
  }
}

// ---------------- cam body (256 threads, 16 KB LDS): E = Wc G Wc^T, softmax, M1 ([d][o]) ----------------
__device__ __forceinline__ void cam_body(const float* __restrict__ G,
                                         const float* __restrict__ w_cam,
                                         const float* __restrict__ w_bn,
                                         float* __restrict__ m1,
                                         int b, float* buf) {
  const int t = threadIdx.x;
#pragma unroll
  for (int i = 0; i < 16; ++i) {
    int idx = t + i * 256;
    buf[idx] = G[(size_t)b * 4096 + idx];
  }
  __syncthreads();
  const int lane = t & 63, rg = (t >> 6) * 16;
  float acc[16];
#pragma unroll
  for (int r = 0; r < 16; ++r) acc[r] = 0.f;
  for (int c = 0; c < 64; ++c) {
    float g = buf[c * 64 + lane];
#pragma unroll
    for (int r = 0; r < 16; ++r) acc[r] += w_cam[(rg + r) * 64 + c] * g;
  }
  __syncthreads();
#pragma unroll
  for (int r = 0; r < 16; ++r) buf[(rg + r) * 64 + lane] = acc[r];   // T1
  __syncthreads();
#pragma unroll
  for (int r = 0; r < 16; ++r) acc[r] = 0.f;
  for (int d = 0; d < 64; ++d) {
    float wl = w_cam[lane * 64 + d];
#pragma unroll
    for (int r = 0; r < 16; ++r) acc[r] += buf[(rg + r) * 64 + d] * wl;
  }
  __syncthreads();
#pragma unroll
  for (int r = 0; r < 16; ++r) buf[(rg + r) * 64 + lane] = acc[r];   // E
  __syncthreads();
  {
    int row = t >> 2, c0 = (t & 3) * 16;
    float v[16];
    float mx = -1e30f;
#pragma unroll
    for (int j = 0; j < 16; ++j) { v[j] = buf[row * 64 + c0 + j]; mx = fmaxf(mx, v[j]); }
    mx = fmaxf(mx, __shfl_xor(mx, 1));
    mx = fmaxf(mx, __shfl_xor(mx, 2));
    float s = 0.f;
#pragma unroll
    for (int j = 0; j < 16; ++j) { v[j] = __expf(v[j] - mx); s += v[j]; }
    s += __shfl_xor(s, 1);
    s += __shfl_xor(s, 2);
    float inv = 1.f / s;
#pragma unroll
    for (int j = 0; j < 16; ++j) buf[row * 64 + c0 + j] = v[j] * inv;  // attn
  }
  __syncthreads();
  float a2[16];
#pragma unroll
  for (int dd = 0; dd < 16; ++dd) a2[dd] = 0.f;
  for (int r = 0; r < 64; ++r) {
    float wv = w_bn[lane * 128 + r];
#pragma unroll
    for (int dd = 0; dd < 16; ++dd) a2[dd] += wv * buf[r * 64 + rg + dd];
  }
  float* mb = m1 + (size_t)b * 4096;
#pragma unroll
  for (int dd = 0; dd < 16; ++dd) mb[(rg + dd) * 64 + lane] = a2[dd];
}

// ---------------- K2: [cam | prep]; prep: q/k/vp via MFMA, fa-exact fragment layouts ----------------
__global__ __launch_bounds__(256) void prep_cam_kernel(const float* __restrict__ x,
                                                       const char* __restrict__ wall,
                                                       char* __restrict__ qd2,
                                                       char* __restrict__ kd2,
                                                       char* __restrict__ vpd2,
                                                       const float* __restrict__ G,
                                                       const float* __restrict__ w_cam,
                                                       const float* __restrict__ w_bn,
                                                       float* __restrict__ m1) {
  __shared__ float buf[4096];
  const int bxx = blockIdx.x;
  if (bxx < 8) {
    cam_body(G, w_cam, w_bn, m1, bxx, buf);
    return;
  }
  const int bx = bxx - 8;
  const int b = bx >> 5, nt2 = bx & 31;
  const int t = threadIdx.x;
  const int wv = t >> 6, l = t & 63, lo5 = l & 31, hi = l >> 5;
  const int chunk = nt2 * 4 + wv;        // 0..127, 32-wide n chunk
  const int n0 = chunk * 32;
  const int tt = chunk >> 1;
  const int n = n0 + lo5;
  const float* xb = x + (size_t)b * C * HW;

  f32x16 fz;
#pragma unroll
  for (int r = 0; r < 16; ++r) fz[r] = 0.f;

  bf16x8 xf[4];
#pragma unroll
  for (int kc = 0; kc < 4; ++kc) {
    float xv[8];
#pragma unroll
    for (int j = 0; j < 8; ++j)
      xv[j] = xb[(size_t)(kc * 16 + hi * 8 + j) * HW + n];
    uint4 u;
    u.x = cvtpk(xv[0], xv[1]); u.y = cvtpk(xv[2], xv[3]);
    u.z = cvtpk(xv[4], xv[5]); u.w = cvtpk(xv[6], xv[7]);
    xf[kc] = __builtin_bit_cast(bf16x8, u);
  }

#pragma unroll
  for (int ot = 0; ot < 4; ++ot) {
    f32x16 acc = fz;
#pragma unroll
    for (int kc = 0; kc < 4; ++kc) {
      bf16x8 wf = *(const bf16x8*)(wall + ((ot << 2) | kc) * 1024 + l * 16);
      acc = (ot < 2) ? mfma_bf16(wf, xf[kc], acc)    // D[col=n][row=out]
                     : mfma_bf16(xf[kc], wf, acc);   // D[col=c][row=m]
    }
    uint wlo[8], whi[8];
#pragma unroll
    for (int i2 = 0; i2 < 8; ++i2) {
      uint w = cvtpk(acc[2 * i2], acc[2 * i2 + 1]);
      uint p = __shfl_xor(w, 32);
      wlo[i2] = hi ? p : w;
      whi[i2] = hi ? w : p;
    }
    uint4 u40, u41;
    u40.x = hi ? wlo[4] : wlo[0];
    u40.y = hi ? wlo[5] : wlo[1];
    u40.z = hi ? whi[4] : whi[0];
    u40.w = hi ? whi[5] : whi[1];
    u41.x = hi ? wlo[6] : wlo[2];
    u41.y = hi ? wlo[7] : wlo[3];
    u41.z = hi ? whi[6] : whi[2];
    u41.w = hi ? whi[7] : whi[3];
    const int e0 = hi * 2;
    if (ot == 0) {
      char* p = qd2 + ((size_t)b * HW + n) * 64;
      *(uint4*)(p + e0 * 16) = u40;
      *(uint4*)(p + (e0 + 1) * 16) = u41;
    } else if (ot == 1) {
      char* p = kd2 + ((size_t)(b * 64 + tt)) * 4096 + (chunk & 1) * 2048 + (n & 31) * 16;
      *(uint4*)(p + e0 * 512) = u40;
      *(uint4*)(p + (e0 + 1) * 512) = u41;
    } else {
      int c = ((ot - 2) << 5) + lo5;
      int oct0 = (chunk & 1) * 4;
      char* p = vpd2 + ((size_t)(b * 64 + tt)) * 8192 + (c >> 5) * 4096 + (c & 31) * 16;
      *(uint4*)(p + (oct0 + e0) * 512) = u40;
      *(uint4*)(p + (oct0 + e0 + 1) * 512) = u41;
    }
  }
}

// ---------------- SAM flash attention: direct global->reg fragments, no LDS/barriers ----------------
__global__ __launch_bounds__(256) void fa_kernel(const char* __restrict__ qd2,
                                                 const char* __restrict__ kd2,
                                                 const char* __restrict__ vpd2,
                                                 char* __restrict__ op,
                                                 float* __restrict__ lp) {
  const int t = threadIdx.x;
  const int l = t & 63, lo5 = l & 31, hi = l >> 5;
  const int wv = t >> 6;
  const int bx = blockIdx.x;
  const int g = (bx & 7) | ((bx >> 8) << 3);   // XCD-aligned: group g lives on XCD g&7
  const int qt = (bx >> 3) & 31;
  const int b = g >> 2, kvs = g & 3;
  const int nq = qt * 128 + wv * 32 + lo5;

  const char* qb = qd2 + ((size_t)b * HW + nq) * 64;
  bf16x8 qf0 = *(const bf16x8*)(qb + hi * 16);
  bf16x8 qf1 = *(const bf16x8*)(qb + 32 + hi * 16);

  f32x16 fz;
#pragma unroll
  for (int r = 0; r < 16; ++r) fz[r] = 0.f;
  f32x16 o0 = fz, o1 = fz;
  float lrun = 0.f;

  const char* kbase = kd2 + ((size_t)(b * 64 + kvs * 16)) * 4096 + l * 16;
  const char* vbase = vpd2 + ((size_t)(b * 64 + kvs * 16)) * 8192 + l * 16;

  bf16x8 kf0 = *(const bf16x8*)(kbase);
  bf16x8 kf1 = *(const bf16x8*)(kbase + 1024);
  bf16x8 kf2 = *(const bf16x8*)(kbase + 2048);
  bf16x8 kf3 = *(const bf16x8*)(kbase + 3072);

#pragma unroll 1
  for (int i = 0; i < 16; ++i) {
    bf16x8 kn0, kn1, kn2, kn3;
    if (i < 15) {
      const char* kn = kbase + (size_t)(i + 1) * 4096;
      kn0 = *(const bf16x8*)(kn);
      kn1 = *(const bf16x8*)(kn + 1024);
      kn2 = *(const bf16x8*)(kn + 2048);
      kn3 = *(const bf16x8*)(kn + 3072);
    }
    const char* vb = vbase + (size_t)i * 8192;
    bf16x8 vfa[4], vfb[4];
#pragma unroll
    for (int ks = 0; ks < 4; ++ks) {
      vfa[ks] = *(const bf16x8*)(vb + ks * 1024);
      vfb[ks] = *(const bf16x8*)(vb + 4096 + ks * 1024);
    }
    f32x16 s0 = mfma_bf16(kf0, qf0, fz);
    s0 = mfma_bf16(kf1, qf1, s0);
    f32x16 s1 = mfma_bf16(kf2, qf0, fz);
    s1 = mfma_bf16(kf3, qf1, s1);
    float ps = 0.f;
#pragma unroll
    for (int r = 0; r < 16; ++r) {
      s0[r] = __builtin_amdgcn_exp2f(s0[r]);
      ps += s0[r];
    }
#pragma unroll
    for (int r = 0; r < 16; ++r) {
      s1[r] = __builtin_amdgcn_exp2f(s1[r]);
      ps += s1[r];
    }
    lrun += ps;                    // lane-local; cross-half merge once at end
#pragma unroll
    for (int ks = 0; ks < 4; ++ks) {
      const f32x16& pm = (ks < 2) ? s0 : s1;
      const int rb = (ks & 1) * 8;
      uint w0 = cvtpk(pm[rb + 0], pm[rb + 1]);
      uint w1 = cvtpk(pm[rb + 2], pm[rb + 3]);
      uint w2 = cvtpk(pm[rb + 4], pm[rb + 5]);
      uint w3 = cvtpk(pm[rb + 6], pm[rb + 7]);
      uint x0 = __shfl_xor(w0, 32);
      uint x1 = __shfl_xor(w1, 32);
      uint x2 = __shfl_xor(w2, 32);
      uint x3 = __shfl_xor(w3, 32);
      uint4 fw;
      fw.x = hi ? x2 : w0;
      fw.y = hi ? x3 : w1;
      fw.z = hi ? w2 : x0;
      fw.w = hi ? w3 : x1;
      bf16x8 pf = __builtin_bit_cast(bf16x8, fw);
      o0 = mfma_bf16(vfa[ks], pf, o0);
      o1 = mfma_bf16(vfb[ks], pf, o1);
    }
    kf0 = kn0; kf1 = kn1; kf2 = kn2; kf3 = kn3;
  }
  lrun += __shfl_xor(lrun, 32);

  ushort* opu = (ushort*)op;
  const size_t obase = ((size_t)(b * 64) * 4 + kvs) * HW + nq;
#pragma unroll
  for (int r = 0; r < 16; ++r) {
    int c0 = (r & 3) + 8 * (r >> 2) + 4 * hi;
    opu[obase + (size_t)c0 * 4 * HW] = bfb(o0[r]);
    opu[obase + (size_t)(c0 + 32) * 4 * HW] = bfb(o1[r]);
  }
  if (hi == 0) lp[(size_t)(kvs * 8 + b) * HW + nq] = lrun;
}

// ---------------- epilogue: out = x + M1@x + merge(op)/merge(l) ----------------
__global__ __launch_bounds__(256) void final_kernel(const float* __restrict__ x,
                                                    const float* __restrict__ m1,
                                                    const char* __restrict__ op,
                                                    const float* __restrict__ lp,
                                                    float* __restrict__ outp) {
  __shared__ __align__(16) float xt[4096];
  __shared__ __align__(16) float ms[4096];
  const int b = blockIdx.y, tt = blockIdx.x, t = threadIdx.x;
  const float4* xg = (const float4*)(x + (size_t)b * C * HW);
  float4* xt4 = (float4*)xt;
#pragma unroll
  for (int i = 0; i < 4; ++i) {
    int idx = t + i * 256;
    int c = idx >> 4, ng = idx & 15;
    xt4[c * 16 + (ng ^ (c & 15))] = xg[c * 1024 + tt * 16 + ng];
  }
  float4* ms4 = (float4*)ms;
  const float4* mg = (const float4*)(m1 + (size_t)b * 4096);
#pragma unroll
  for (int i = 0; i < 4; ++i) ms4[t + i * 256] = mg[t + i * 256];
  __syncthreads();
  const int n = t & 63, sub = t >> 6;
  const int gn = tt * 64 + n;
  float xr[64];
#pragma unroll
  for (int c = 0; c < 64; ++c)
    xr[c] = xt[c * 64 + (((n >> 2) ^ (c & 15)) << 2) + (n & 3)];
  float lsum = 0.f;
#pragma unroll
  for (int kvs = 0; kvs < 4; ++kvs) lsum += lp[(size_t)(kvs * 8 + b) * HW + gn];
  float linv = 1.f / lsum;
  const ushort* opu = (const ushort*)op;
  float acc[16];
#pragma unroll
  for (int ci = 0; ci < 16; ++ci) {
    int c = sub * 16 + ci;
    float osum = 0.f;
#pragma unroll
    for (int kvs = 0; kvs < 4; ++kvs) {
      ushort u = opu[((size_t)(b * 64 + c) * 4 + kvs) * HW + gn];
      osum += __builtin_bit_cast(float, (uint)u << 16);
    }
    acc[ci] = xr[c] + osum * linv;
  }
  for (int d = 0; d < 64; ++d) {
    float xv = xr[d];
    const float4* mr = (const float4*)(ms + d * 64 + sub * 16);
#pragma unroll
    for (int c4 = 0; c4 < 4; ++c4) {
      float4 mv = mr[c4];
      acc[c4 * 4 + 0] += mv.x * xv;
      acc[c4 * 4 + 1] += mv.y * xv;
      acc[c4 * 4 + 2] += mv.z * xv;
      acc[c4 * 4 + 3] += mv.w * xv;
    }
  }
  float* ob = outp + (size_t)b * C * HW + gn;
#pragma unroll
  for (int ci = 0; ci < 16; ++ci)
    ob[(size_t)(sub * 16 + ci) * HW] = acc[ci];
}

extern "C" void kernel_launch(void* const* d_in, const int* in_sizes, int n_in,
                              void* d_out, int out_size, void* d_ws, size_t ws_size,
                              hipStream_t stream) {
  const float* x     = (const float*)d_in[0];
  const float* w_cam = (const float*)d_in[1];
  const float* w_q   = (const float*)d_in[2];
  const float* w_k   = (const float*)d_in[3];
  const float* w_v   = (const float*)d_in[4];
  const float* w_bn  = (const float*)d_in[5];
  float* out = (float*)d_out;
  char* wsb = (char*)d_ws;

  // workspace layout (bytes) — total ~24.8 MB
  char*  wall = wsb;                               // 16 KB  wall fragments
  float* m1   = (float*)(wsb + 16384);             // 128 KB
  float* G    = (float*)(wsb + 147456);            // 128 KB
  char*  qd2  = wsb + 278528;                      // 2 MB
  char*  kd2  = qd2 + 2097152;                     // 2 MB
  char*  vpd2 = kd2 + 2097152;                     // 4 MB
  float* lp   = (float*)(vpd2 + 4194304);          // 512 KB
  char*  op   = (char*)lp + 524288;                // 16 MB

  gram_fold_kernel<<<9, 1024, 0, stream>>>(x, G, w_bn, w_q, w_k, w_v, wall);
  prep_cam_kernel<<<264, 256, 0, stream>>>(x, wall, qd2, kd2, vpd2, G, w_cam, w_bn, m1);
  fa_kernel<<<1024, 256, 0, stream>>>(qd2, kd2, vpd2, op, lp);
  final_kernel<<<dim3(64, BB), 256, 0, stream>>>(x, m1, op, lp, out);
}

// Round 14
// 119.680 us; speedup vs baseline: 1.3458x; 1.1331x over previous
//
#include <hip/hip_runtime.h>

#define BB 8
#define C 64
#define HW 4096

typedef __attribute__((ext_vector_type(8))) __bf16 bf16x8;
typedef __attribute__((ext_vector_type(16))) float f32x16;
typedef unsigned int uint;
typedef unsigned short ushort;

__device__ __forceinline__ ushort bfb(float f) {
  return __builtin_bit_cast(ushort, (__bf16)f);
}
__device__ __forceinline__ uint pk2(float a, float b) {
  return (uint)bfb(a) | ((uint)bfb(b) << 16);
}
__device__ __forceinline__ uint cvtpk(float a, float b) {
  uint r;
  asm("v_cvt_pk_bf16_f32 %0, %1, %2" : "=v"(r) : "v"(a), "v"(b));
  return r;
}
__device__ __forceinline__ f32x16 mfma_bf16(bf16x8 a, bf16x8 b, f32x16 c) {
  return __builtin_amdgcn_mfma_f32_32x32x16_bf16(a, b, c, 0, 0, 0);
}

// ---------------- K1: [fold | gram] ----------------
// blocks 0..3: fold (4 slots each = 16 wall fragments).
// blocks 4..67: gram — 8 blocks per b, each covers K=512 (4 waves x K=128),
// split-x h+l bf16 MFMA, 4-slot LDS reduce, ONE partial store per block
// (8 partials/b). No memset, no atomics, no serial reduce tails.
__global__ __launch_bounds__(256) void gram_fold_kernel(const float* __restrict__ x,
                                                        float* __restrict__ Gp,
                                                        const float* __restrict__ w_bn,
                                                        const float* __restrict__ w_q,
                                                        const float* __restrict__ w_k,
                                                        const float* __restrict__ w_v,
                                                        char* __restrict__ wall) {
  __shared__ float slots[4][4096];   // 64 KB
  const int bxx = blockIdx.x;
  const int t = threadIdx.x;
  if (bxx < 4) {
    // ---- fold ----
    const int slot = bxx * 4 + (t >> 6);   // ot*4 + kc
    const int ot = slot >> 2, kc = slot & 3;
    const int l = t & 63, lo5 = l & 31, hi = l >> 5;
    float v[8];
    if (ot == 0) {
#pragma unroll
      for (int j = 0; j < 8; ++j)
        v[j] = 1.44269504088896f * w_q[lo5 * 64 + kc * 16 + hi * 8 + j];
    } else if (ot == 1) {
#pragma unroll
      for (int j = 0; j < 8; ++j) v[j] = w_k[lo5 * 64 + kc * 16 + hi * 8 + j];
    } else {
      int c = (ot - 2) * 32 + lo5;
#pragma unroll
      for (int j = 0; j < 8; ++j) {
        int d = kc * 16 + hi * 8 + j;
        float acc = 0.f;
        for (int e = 0; e < 64; ++e) acc += w_bn[c * 128 + 64 + e] * w_v[e * 64 + d];
        v[j] = acc;
      }
    }
    uint4 w;
    w.x = pk2(v[0], v[1]); w.y = pk2(v[2], v[3]);
    w.z = pk2(v[4], v[5]); w.w = pk2(v[6], v[7]);
    *(uint4*)(wall + slot * 1024 + l * 16) = w;
    return;
  }
  // ---- gram ----
  const int bx = bxx - 4;                 // 0..63
  const int b = bx >> 3, kb = bx & 7;
  const int w = t >> 6, l = t & 63, lo5 = l & 31, hi = l >> 5;
  const int k0 = kb * 512 + w * 128;
  const float* xb = x + (size_t)b * C * HW;
  f32x16 fz;
#pragma unroll
  for (int r = 0; r < 16; ++r) fz[r] = 0.f;
  f32x16 a00 = fz, a01 = fz, a10 = fz, a11 = fz;
#pragma unroll 1
  for (int kc = 0; kc < 8; ++kc) {
    int nb = k0 + kc * 16 + hi * 8;
    const float4* p0 = (const float4*)(xb + (size_t)lo5 * HW + nb);
    const float4* p1 = (const float4*)(xb + (size_t)(32 + lo5) * HW + nb);
    float v0[8], v1[8];
    {
      float4 a = p0[0], bq = p0[1];
      v0[0] = a.x; v0[1] = a.y; v0[2] = a.z; v0[3] = a.w;
      v0[4] = bq.x; v0[5] = bq.y; v0[6] = bq.z; v0[7] = bq.w;
      float4 c = p1[0], d = p1[1];
      v1[0] = c.x; v1[1] = c.y; v1[2] = c.z; v1[3] = c.w;
      v1[4] = d.x; v1[5] = d.y; v1[6] = d.z; v1[7] = d.w;
    }
    uint4 uh0, ul0, uh1, ul1;
    {
      float h[8], e[8];
#pragma unroll
      for (int j = 0; j < 8; ++j) { h[j] = (float)(__bf16)v0[j]; e[j] = v0[j] - h[j]; }
      uh0.x = pk2(h[0], h[1]); uh0.y = pk2(h[2], h[3]); uh0.z = pk2(h[4], h[5]); uh0.w = pk2(h[6], h[7]);
      ul0.x = cvtpk(e[0], e[1]); ul0.y = cvtpk(e[2], e[3]); ul0.z = cvtpk(e[4], e[5]); ul0.w = cvtpk(e[6], e[7]);
#pragma unroll
      for (int j = 0; j < 8; ++j) { h[j] = (float)(__bf16)v1[j]; e[j] = v1[j] - h[j]; }
      uh1.x = pk2(h[0], h[1]); uh1.y = pk2(h[2], h[3]); uh1.z = pk2(h[4], h[5]); uh1.w = pk2(h[6], h[7]);
      ul1.x = cvtpk(e[0], e[1]); ul1.y = cvtpk(e[2], e[3]); ul1.z = cvtpk(e[4], e[5]); ul1.w = cvtpk(e[6], e[7]);
    }
    bf16x8 f0h = __builtin_bit_cast(bf16x8, uh0);
    bf16x8 f0l = __builtin_bit_cast(bf16x8, ul0);
    bf16x8 f1h = __builtin_bit_cast(bf16x8, uh1);
    bf16x8 f1l = __builtin_bit_cast(bf16x8, ul1);
    a00 = mfma_bf16(f0h, f0h, a00); a00 = mfma_bf16(f0h, f0l, a00); a00 = mfma_bf16(f0l, f0h, a00);
    a01 = mfma_bf16(f0h, f1h, a01); a01 = mfma_bf16(f0h, f1l, a01); a01 = mfma_bf16(f0l, f1h, a01);
    a10 = mfma_bf16(f1h, f0h, a10); a10 = mfma_bf16(f1h, f0l, a10); a10 = mfma_bf16(f1l, f0h, a10);
    a11 = mfma_bf16(f1h, f1h, a11); a11 = mfma_bf16(f1h, f1l, a11); a11 = mfma_bf16(f1l, f1h, a11);
  }
  // own slot per wave, then block reduce
#pragma unroll
  for (int r = 0; r < 16; ++r) {
    int row = (r & 3) + 8 * (r >> 2) + 4 * hi;
    slots[w][row * 64 + lo5] = a00[r];
    slots[w][row * 64 + 32 + lo5] = a01[r];
    slots[w][(32 + row) * 64 + lo5] = a10[r];
    slots[w][(32 + row) * 64 + 32 + lo5] = a11[r];
  }
  __syncthreads();
  float* g = Gp + (size_t)(b * 8 + kb) * 4096;
#pragma unroll
  for (int i = 0; i < 16; ++i) {
    int idx = t + i * 256;
    g[idx] = slots[0][idx] + slots[1][idx] + slots[2][idx] + slots[3][idx];
  }
}

// ---------------- cam body (256 threads, 16 KB LDS): reduce 8 partials, E, softmax, M1 ----------------
__device__ __forceinline__ void cam_body(const float* __restrict__ Gp,
                                         const float* __restrict__ w_cam,
                                         const float* __restrict__ w_bn,
                                         float* __restrict__ m1,
                                         int b, float* buf) {
  const int t = threadIdx.x;
#pragma unroll
  for (int i = 0; i < 16; ++i) {
    int idx = t + i * 256;
    float s = 0.f;
#pragma unroll
    for (int p = 0; p < 8; ++p)
      s += Gp[(size_t)(b * 8 + p) * 4096 + idx];
    buf[idx] = s;
  }
  __syncthreads();
  const int lane = t & 63, rg = (t >> 6) * 16;
  float acc[16];
#pragma unroll
  for (int r = 0; r < 16; ++r) acc[r] = 0.f;
  for (int c = 0; c < 64; ++c) {
    float g = buf[c * 64 + lane];
#pragma unroll
    for (int r = 0; r < 16; ++r) acc[r] += w_cam[(rg + r) * 64 + c] * g;
  }
  __syncthreads();
#pragma unroll
  for (int r = 0; r < 16; ++r) buf[(rg + r) * 64 + lane] = acc[r];   // T1
  __syncthreads();
#pragma unroll
  for (int r = 0; r < 16; ++r) acc[r] = 0.f;
  for (int d = 0; d < 64; ++d) {
    float wl = w_cam[lane * 64 + d];
#pragma unroll
    for (int r = 0; r < 16; ++r) acc[r] += buf[(rg + r) * 64 + d] * wl;
  }
  __syncthreads();
#pragma unroll
  for (int r = 0; r < 16; ++r) buf[(rg + r) * 64 + lane] = acc[r];   // E
  __syncthreads();
  {
    int row = t >> 2, c0 = (t & 3) * 16;
    float v[16];
    float mx = -1e30f;
#pragma unroll
    for (int j = 0; j < 16; ++j) { v[j] = buf[row * 64 + c0 + j]; mx = fmaxf(mx, v[j]); }
    mx = fmaxf(mx, __shfl_xor(mx, 1));
    mx = fmaxf(mx, __shfl_xor(mx, 2));
    float s = 0.f;
#pragma unroll
    for (int j = 0; j < 16; ++j) { v[j] = __expf(v[j] - mx); s += v[j]; }
    s += __shfl_xor(s, 1);
    s += __shfl_xor(s, 2);
    float inv = 1.f / s;
#pragma unroll
    for (int j = 0; j < 16; ++j) buf[row * 64 + c0 + j] = v[j] * inv;  // attn
  }
  __syncthreads();
  float a2[16];
#pragma unroll
  for (int dd = 0; dd < 16; ++dd) a2[dd] = 0.f;
  for (int r = 0; r < 64; ++r) {
    float wv = w_bn[lane * 128 + r];
#pragma unroll
    for (int dd = 0; dd < 16; ++dd) a2[dd] += wv * buf[r * 64 + rg + dd];
  }
  float* mb = m1 + (size_t)b * 4096;
#pragma unroll
  for (int dd = 0; dd < 16; ++dd) mb[(rg + dd) * 64 + lane] = a2[dd];
}

// ---------------- K2: [cam | prep]; prep: q/k/vp via MFMA, fa-exact fragment layouts ----------------
__global__ __launch_bounds__(256) void prep_cam_kernel(const float* __restrict__ x,
                                                       const char* __restrict__ wall,
                                                       char* __restrict__ qd2,
                                                       char* __restrict__ kd2,
                                                       char* __restrict__ vpd2,
                                                       const float* __restrict__ Gp,
                                                       const float* __restrict__ w_cam,
                                                       const float* __restrict__ w_bn,
                                                       float* __restrict__ m1) {
  __shared__ float buf[4096];
  const int bxx = blockIdx.x;
  if (bxx < 8) {
    cam_body(Gp, w_cam, w_bn, m1, bxx, buf);
    return;
  }
  const int bx = bxx - 8;
  const int b = bx >> 5, nt2 = bx & 31;
  const int t = threadIdx.x;
  const int wv = t >> 6, l = t & 63, lo5 = l & 31, hi = l >> 5;
  const int chunk = nt2 * 4 + wv;        // 0..127, 32-wide n chunk
  const int n0 = chunk * 32;
  const int tt = chunk >> 1;
  const int n = n0 + lo5;
  const float* xb = x + (size_t)b * C * HW;

  f32x16 fz;
#pragma unroll
  for (int r = 0; r < 16; ++r) fz[r] = 0.f;

  bf16x8 xf[4];
#pragma unroll
  for (int kc = 0; kc < 4; ++kc) {
    float xv[8];
#pragma unroll
    for (int j = 0; j < 8; ++j)
      xv[j] = xb[(size_t)(kc * 16 + hi * 8 + j) * HW + n];
    uint4 u;
    u.x = cvtpk(xv[0], xv[1]); u.y = cvtpk(xv[2], xv[3]);
    u.z = cvtpk(xv[4], xv[5]); u.w = cvtpk(xv[6], xv[7]);
    xf[kc] = __builtin_bit_cast(bf16x8, u);
  }

#pragma unroll
  for (int ot = 0; ot < 4; ++ot) {
    f32x16 acc = fz;
#pragma unroll
    for (int kc = 0; kc < 4; ++kc) {
      bf16x8 wf = *(const bf16x8*)(wall + ((ot << 2) | kc) * 1024 + l * 16);
      acc = (ot < 2) ? mfma_bf16(wf, xf[kc], acc)    // D[col=n][row=out]
                     : mfma_bf16(xf[kc], wf, acc);   // D[col=c][row=m]
    }
    uint wlo[8], whi[8];
#pragma unroll
    for (int i2 = 0; i2 < 8; ++i2) {
      uint w = cvtpk(acc[2 * i2], acc[2 * i2 + 1]);
      uint p = __shfl_xor(w, 32);
      wlo[i2] = hi ? p : w;
      whi[i2] = hi ? w : p;
    }
    uint4 u40, u41;
    u40.x = hi ? wlo[4] : wlo[0];
    u40.y = hi ? wlo[5] : wlo[1];
    u40.z = hi ? whi[4] : whi[0];
    u40.w = hi ? whi[5] : whi[1];
    u41.x = hi ? wlo[6] : wlo[2];
    u41.y = hi ? wlo[7] : wlo[3];
    u41.z = hi ? whi[6] : whi[2];
    u41.w = hi ? whi[7] : whi[3];
    const int e0 = hi * 2;
    if (ot == 0) {
      char* p = qd2 + ((size_t)b * HW + n) * 64;
      *(uint4*)(p + e0 * 16) = u40;
      *(uint4*)(p + (e0 + 1) * 16) = u41;
    } else if (ot == 1) {
      char* p = kd2 + ((size_t)(b * 64 + tt)) * 4096 + (chunk & 1) * 2048 + (n & 31) * 16;
      *(uint4*)(p + e0 * 512) = u40;
      *(uint4*)(p + (e0 + 1) * 512) = u41;
    } else {
      int c = ((ot - 2) << 5) + lo5;
      int oct0 = (chunk & 1) * 4;
      char* p = vpd2 + ((size_t)(b * 64 + tt)) * 8192 + (c >> 5) * 4096 + (c & 31) * 16;
      *(uint4*)(p + (oct0 + e0) * 512) = u40;
      *(uint4*)(p + (oct0 + e0 + 1) * 512) = u41;
    }
  }
}

// ---------------- SAM flash attention: direct global->reg fragments, no LDS/barriers ----------------
__global__ __launch_bounds__(256) void fa_kernel(const char* __restrict__ qd2,
                                                 const char* __restrict__ kd2,
                                                 const char* __restrict__ vpd2,
                                                 char* __restrict__ op,
                                                 float* __restrict__ lp) {
  const int t = threadIdx.x;
  const int l = t & 63, lo5 = l & 31, hi = l >> 5;
  const int wv = t >> 6;
  const int bx = blockIdx.x;
  const int g = (bx & 7) | ((bx >> 8) << 3);   // XCD-aligned: group g lives on XCD g&7
  const int qt = (bx >> 3) & 31;
  const int b = g >> 2, kvs = g & 3;
  const int nq = qt * 128 + wv * 32 + lo5;

  const char* qb = qd2 + ((size_t)b * HW + nq) * 64;
  bf16x8 qf0 = *(const bf16x8*)(qb + hi * 16);
  bf16x8 qf1 = *(const bf16x8*)(qb + 32 + hi * 16);

  f32x16 fz;
#pragma unroll
  for (int r = 0; r < 16; ++r) fz[r] = 0.f;
  f32x16 o0 = fz, o1 = fz;
  float lrun = 0.f;

  const char* kbase = kd2 + ((size_t)(b * 64 + kvs * 16)) * 4096 + l * 16;
  const char* vbase = vpd2 + ((size_t)(b * 64 + kvs * 16)) * 8192 + l * 16;

  bf16x8 kf0 = *(const bf16x8*)(kbase);
  bf16x8 kf1 = *(const bf16x8*)(kbase + 1024);
  bf16x8 kf2 = *(const bf16x8*)(kbase + 2048);
  bf16x8 kf3 = *(const bf16x8*)(kbase + 3072);

#pragma unroll 1
  for (int i = 0; i < 16; ++i) {
    bf16x8 kn0, kn1, kn2, kn3;
    if (i < 15) {
      const char* kn = kbase + (size_t)(i + 1) * 4096;
      kn0 = *(const bf16x8*)(kn);
      kn1 = *(const bf16x8*)(kn + 1024);
      kn2 = *(const bf16x8*)(kn + 2048);
      kn3 = *(const bf16x8*)(kn + 3072);
    }
    const char* vb = vbase + (size_t)i * 8192;
    bf16x8 vfa[4], vfb[4];
#pragma unroll
    for (int ks = 0; ks < 4; ++ks) {
      vfa[ks] = *(const bf16x8*)(vb + ks * 1024);
      vfb[ks] = *(const bf16x8*)(vb + 4096 + ks * 1024);
    }
    f32x16 s0 = mfma_bf16(kf0, qf0, fz);
    s0 = mfma_bf16(kf1, qf1, s0);
    f32x16 s1 = mfma_bf16(kf2, qf0, fz);
    s1 = mfma_bf16(kf3, qf1, s1);
    float ps = 0.f;
#pragma unroll
    for (int r = 0; r < 16; ++r) {
      s0[r] = __builtin_amdgcn_exp2f(s0[r]);
      ps += s0[r];
    }
#pragma unroll
    for (int r = 0; r < 16; ++r) {
      s1[r] = __builtin_amdgcn_exp2f(s1[r]);
      ps += s1[r];
    }
    lrun += ps;                    // lane-local; cross-half merge once at end
#pragma unroll
    for (int ks = 0; ks < 4; ++ks) {
      const f32x16& pm = (ks < 2) ? s0 : s1;
      const int rb = (ks & 1) * 8;
      uint w0 = cvtpk(pm[rb + 0], pm[rb + 1]);
      uint w1 = cvtpk(pm[rb + 2], pm[rb + 3]);
      uint w2 = cvtpk(pm[rb + 4], pm[rb + 5]);
      uint w3 = cvtpk(pm[rb + 6], pm[rb + 7]);
      uint x0 = __shfl_xor(w0, 32);
      uint x1 = __shfl_xor(w1, 32);
      uint x2 = __shfl_xor(w2, 32);
      uint x3 = __shfl_xor(w3, 32);
      uint4 fw;
      fw.x = hi ? x2 : w0;
      fw.y = hi ? x3 : w1;
      fw.z = hi ? w2 : x0;
      fw.w = hi ? w3 : x1;
      bf16x8 pf = __builtin_bit_cast(bf16x8, fw);
      o0 = mfma_bf16(vfa[ks], pf, o0);
      o1 = mfma_bf16(vfb[ks], pf, o1);
    }
    kf0 = kn0; kf1 = kn1; kf2 = kn2; kf3 = kn3;
  }
  lrun += __shfl_xor(lrun, 32);

  ushort* opu = (ushort*)op;
  const size_t obase = ((size_t)(b * 64) * 4 + kvs) * HW + nq;
#pragma unroll
  for (int r = 0; r < 16; ++r) {
    int c0 = (r & 3) + 8 * (r >> 2) + 4 * hi;
    opu[obase + (size_t)c0 * 4 * HW] = bfb(o0[r]);
    opu[obase + (size_t)(c0 + 32) * 4 * HW] = bfb(o1[r]);
  }
  if (hi == 0) lp[(size_t)(kvs * 8 + b) * HW + nq] = lrun;
}

// ---------------- epilogue: out = x + M1@x + merge(op)/merge(l) ----------------
__global__ __launch_bounds__(256) void final_kernel(const float* __restrict__ x,
                                                    const float* __restrict__ m1,
                                                    const char* __restrict__ op,
                                                    const float* __restrict__ lp,
                                                    float* __restrict__ outp) {
  __shared__ __align__(16) float xt[4096];
  __shared__ __align__(16) float ms[4096];
  const int b = blockIdx.y, tt = blockIdx.x, t = threadIdx.x;
  const float4* xg = (const float4*)(x + (size_t)b * C * HW);
  float4* xt4 = (float4*)xt;
#pragma unroll
  for (int i = 0; i < 4; ++i) {
    int idx = t + i * 256;
    int c = idx >> 4, ng = idx & 15;
    xt4[c * 16 + (ng ^ (c & 15))] = xg[c * 1024 + tt * 16 + ng];
  }
  float4* ms4 = (float4*)ms;
  const float4* mg = (const float4*)(m1 + (size_t)b * 4096);
#pragma unroll
  for (int i = 0; i < 4; ++i) ms4[t + i * 256] = mg[t + i * 256];
  __syncthreads();
  const int n = t & 63, sub = t >> 6;
  const int gn = tt * 64 + n;
  float xr[64];
#pragma unroll
  for (int c = 0; c < 64; ++c)
    xr[c] = xt[c * 64 + (((n >> 2) ^ (c & 15)) << 2) + (n & 3)];
  float lsum = 0.f;
#pragma unroll
  for (int kvs = 0; kvs < 4; ++kvs) lsum += lp[(size_t)(kvs * 8 + b) * HW + gn];
  float linv = 1.f / lsum;
  const ushort* opu = (const ushort*)op;
  float acc[16];
#pragma unroll
  for (int ci = 0; ci < 16; ++ci) {
    int c = sub * 16 + ci;
    float osum = 0.f;
#pragma unroll
    for (int kvs = 0; kvs < 4; ++kvs) {
      ushort u = opu[((size_t)(b * 64 + c) * 4 + kvs) * HW + gn];
      osum += __builtin_bit_cast(float, (uint)u << 16);
    }
    acc[ci] = xr[c] + osum * linv;
  }
  for (int d = 0; d < 64; ++d) {
    float xv = xr[d];
    const float4* mr = (const float4*)(ms + d * 64 + sub * 16);
#pragma unroll
    for (int c4 = 0; c4 < 4; ++c4) {
      float4 mv = mr[c4];
      acc[c4 * 4 + 0] += mv.x * xv;
      acc[c4 * 4 + 1] += mv.y * xv;
      acc[c4 * 4 + 2] += mv.z * xv;
      acc[c4 * 4 + 3] += mv.w * xv;
    }
  }
  float* ob = outp + (size_t)b * C * HW + gn;
#pragma unroll
  for (int ci = 0; ci < 16; ++ci)
    ob[(size_t)(sub * 16 + ci) * HW] = acc[ci];
}

extern "C" void kernel_launch(void* const* d_in, const int* in_sizes, int n_in,
                              void* d_out, int out_size, void* d_ws, size_t ws_size,
                              hipStream_t stream) {
  const float* x     = (const float*)d_in[0];
  const float* w_cam = (const float*)d_in[1];
  const float* w_q   = (const float*)d_in[2];
  const float* w_k   = (const float*)d_in[3];
  const float* w_v   = (const float*)d_in[4];
  const float* w_bn  = (const float*)d_in[5];
  float* out = (float*)d_out;
  char* wsb = (char*)d_ws;

  // workspace layout (bytes) — total ~24.7 MB
  char*  wall = wsb;                               // 16 KB  wall fragments
  float* m1   = (float*)(wsb + 16384);             // 128 KB
  char*  qd2  = wsb + 147456;                      // 2 MB
  char*  kd2  = qd2 + 2097152;                     // 2 MB
  char*  vpd2 = kd2 + 2097152;                     // 4 MB
  float* lp   = (float*)(vpd2 + 4194304);          // 512 KB
  char*  op   = (char*)lp + 524288;                // 16 MB; Gp aliases first 1 MB
  float* Gp   = (float*)op;                        // 64 partials x 16 KB = 1 MB
  // alias safety: gram_fold writes Gp; prep_cam::cam reads Gp -> m1; fa then
  // overwrites the same bytes as op (stream-ordered after prep_cam); final reads op.

  gram_fold_kernel<<<68, 256, 0, stream>>>(x, Gp, w_bn, w_q, w_k, w_v, wall);
  prep_cam_kernel<<<264, 256, 0, stream>>>(x, wall, qd2, kd2, vpd2, Gp, w_cam, w_bn, m1);
  fa_kernel<<<1024, 256, 0, stream>>>(qd2, kd2, vpd2, op, lp);
  final_kernel<<<dim3(64, BB), 256, 0, stream>>>(x, m1, op, lp, out);
}

// Round 15
// 119.432 us; speedup vs baseline: 1.3486x; 1.0021x over previous
//
#include <hip/hip_runtime.h>

#define BB 8
#define C 64
#define HW 4096

typedef __attribute__((ext_vector_type(8))) __bf16 bf16x8;
typedef __attribute__((ext_vector_type(16))) float f32x16;
typedef unsigned int uint;
typedef unsigned short ushort;

__device__ __forceinline__ ushort bfb(float f) {
  return __builtin_bit_cast(ushort, (__bf16)f);
}
__device__ __forceinline__ uint pk2(float a, float b) {
  return (uint)bfb(a) | ((uint)bfb(b) << 16);
}
__device__ __forceinline__ uint cvtpk(float a, float b) {
  uint r;
  asm("v_cvt_pk_bf16_f32 %0, %1, %2" : "=v"(r) : "v"(a), "v"(b));
  return r;
}
__device__ __forceinline__ f32x16 mfma_bf16(bf16x8 a, bf16x8 b, f32x16 c) {
  return __builtin_amdgcn_mfma_f32_32x32x16_bf16(a, b, c, 0, 0, 0);
}

// ---------------- K1: [fold | gram] ----------------
// blocks 0..3: fold (4 slots each = 16 wall fragments).
// blocks 4..67: gram — 8 blocks per b, each covers K=512 (4 waves x K=128),
// split-x h+l bf16 MFMA, per-wave LDS slot, ONE partial store per block.
__global__ __launch_bounds__(256) void gram_fold_kernel(const float* __restrict__ x,
                                                        float* __restrict__ Gp,
                                                        const float* __restrict__ w_bn,
                                                        const float* __restrict__ w_q,
                                                        const float* __restrict__ w_k,
                                                        const float* __restrict__ w_v,
                                                        char* __restrict__ wall) {
  __shared__ float slots[4][4096];   // 64 KB
  const int bxx = blockIdx.x;
  const int t = threadIdx.x;
  if (bxx < 4) {
    // ---- fold ----
    const int slot = bxx * 4 + (t >> 6);   // ot*4 + kc
    const int ot = slot >> 2, kc = slot & 3;
    const int l = t & 63, lo5 = l & 31, hi = l >> 5;
    float v[8];
    if (ot == 0) {
#pragma unroll
      for (int j = 0; j < 8; ++j)
        v[j] = 1.44269504088896f * w_q[lo5 * 64 + kc * 16 + hi * 8 + j];
    } else if (ot == 1) {
#pragma unroll
      for (int j = 0; j < 8; ++j) v[j] = w_k[lo5 * 64 + kc * 16 + hi * 8 + j];
    } else {
      int c = (ot - 2) * 32 + lo5;
#pragma unroll
      for (int j = 0; j < 8; ++j) {
        int d = kc * 16 + hi * 8 + j;
        float acc = 0.f;
        for (int e = 0; e < 64; ++e) acc += w_bn[c * 128 + 64 + e] * w_v[e * 64 + d];
        v[j] = acc;
      }
    }
    uint4 w;
    w.x = pk2(v[0], v[1]); w.y = pk2(v[2], v[3]);
    w.z = pk2(v[4], v[5]); w.w = pk2(v[6], v[7]);
    *(uint4*)(wall + slot * 1024 + l * 16) = w;
    return;
  }
  // ---- gram ----
  const int bx = bxx - 4;                 // 0..63
  const int b = bx >> 3, kb = bx & 7;
  const int w = t >> 6, l = t & 63, lo5 = l & 31, hi = l >> 5;
  const int k0 = kb * 512 + w * 128;
  const float* xb = x + (size_t)b * C * HW;
  f32x16 fz;
#pragma unroll
  for (int r = 0; r < 16; ++r) fz[r] = 0.f;
  f32x16 a00 = fz, a01 = fz, a10 = fz, a11 = fz;
#pragma unroll 1
  for (int kc = 0; kc < 8; ++kc) {
    int nb = k0 + kc * 16 + hi * 8;
    const float4* p0 = (const float4*)(xb + (size_t)lo5 * HW + nb);
    const float4* p1 = (const float4*)(xb + (size_t)(32 + lo5) * HW + nb);
    float v0[8], v1[8];
    {
      float4 a = p0[0], bq = p0[1];
      v0[0] = a.x; v0[1] = a.y; v0[2] = a.z; v0[3] = a.w;
      v0[4] = bq.x; v0[5] = bq.y; v0[6] = bq.z; v0[7] = bq.w;
      float4 c = p1[0], d = p1[1];
      v1[0] = c.x; v1[1] = c.y; v1[2] = c.z; v1[3] = c.w;
      v1[4] = d.x; v1[5] = d.y; v1[6] = d.z; v1[7] = d.w;
    }
    uint4 uh0, ul0, uh1, ul1;
    {
      float h[8], e[8];
#pragma unroll
      for (int j = 0; j < 8; ++j) { h[j] = (float)(__bf16)v0[j]; e[j] = v0[j] - h[j]; }
      uh0.x = pk2(h[0], h[1]); uh0.y = pk2(h[2], h[3]); uh0.z = pk2(h[4], h[5]); uh0.w = pk2(h[6], h[7]);
      ul0.x = cvtpk(e[0], e[1]); ul0.y = cvtpk(e[2], e[3]); ul0.z = cvtpk(e[4], e[5]); ul0.w = cvtpk(e[6], e[7]);
#pragma unroll
      for (int j = 0; j < 8; ++j) { h[j] = (float)(__bf16)v1[j]; e[j] = v1[j] - h[j]; }
      uh1.x = pk2(h[0], h[1]); uh1.y = pk2(h[2], h[3]); uh1.z = pk2(h[4], h[5]); uh1.w = pk2(h[6], h[7]);
      ul1.x = cvtpk(e[0], e[1]); ul1.y = cvtpk(e[2], e[3]); ul1.z = cvtpk(e[4], e[5]); ul1.w = cvtpk(e[6], e[7]);
    }
    bf16x8 f0h = __builtin_bit_cast(bf16x8, uh0);
    bf16x8 f0l = __builtin_bit_cast(bf16x8, ul0);
    bf16x8 f1h = __builtin_bit_cast(bf16x8, uh1);
    bf16x8 f1l = __builtin_bit_cast(bf16x8, ul1);
    a00 = mfma_bf16(f0h, f0h, a00); a00 = mfma_bf16(f0h, f0l, a00); a00 = mfma_bf16(f0l, f0h, a00);
    a01 = mfma_bf16(f0h, f1h, a01); a01 = mfma_bf16(f0h, f1l, a01); a01 = mfma_bf16(f0l, f1h, a01);
    a10 = mfma_bf16(f1h, f0h, a10); a10 = mfma_bf16(f1h, f0l, a10); a10 = mfma_bf16(f1l, f0h, a10);
    a11 = mfma_bf16(f1h, f1h, a11); a11 = mfma_bf16(f1h, f1l, a11); a11 = mfma_bf16(f1l, f1h, a11);
  }
#pragma unroll
  for (int r = 0; r < 16; ++r) {
    int row = (r & 3) + 8 * (r >> 2) + 4 * hi;
    slots[w][row * 64 + lo5] = a00[r];
    slots[w][row * 64 + 32 + lo5] = a01[r];
    slots[w][(32 + row) * 64 + lo5] = a10[r];
    slots[w][(32 + row) * 64 + 32 + lo5] = a11[r];
  }
  __syncthreads();
  float* g = Gp + (size_t)(b * 8 + kb) * 4096;
#pragma unroll
  for (int i = 0; i < 16; ++i) {
    int idx = t + i * 256;
    g[idx] = slots[0][idx] + slots[1][idx] + slots[2][idx] + slots[3][idx];
  }
}

// ---------------- cam body (256 threads, 16 KB LDS): reduce 8 partials, E, softmax, M1 ----------------
__device__ __forceinline__ void cam_body(const float* __restrict__ Gp,
                                         const float* __restrict__ w_cam,
                                         const float* __restrict__ w_bn,
                                         float* __restrict__ m1,
                                         int b, float* buf) {
  const int t = threadIdx.x;
#pragma unroll
  for (int i = 0; i < 16; ++i) {
    int idx = t + i * 256;
    float s = 0.f;
#pragma unroll
    for (int p = 0; p < 8; ++p)
      s += Gp[(size_t)(b * 8 + p) * 4096 + idx];
    buf[idx] = s;
  }
  __syncthreads();
  const int lane = t & 63, rg = (t >> 6) * 16;
  float acc[16];
#pragma unroll
  for (int r = 0; r < 16; ++r) acc[r] = 0.f;
  for (int c = 0; c < 64; ++c) {
    float g = buf[c * 64 + lane];
#pragma unroll
    for (int r = 0; r < 16; ++r) acc[r] += w_cam[(rg + r) * 64 + c] * g;
  }
  __syncthreads();
#pragma unroll
  for (int r = 0; r < 16; ++r) buf[(rg + r) * 64 + lane] = acc[r];   // T1
  __syncthreads();
#pragma unroll
  for (int r = 0; r < 16; ++r) acc[r] = 0.f;
  for (int d = 0; d < 64; ++d) {
    float wl = w_cam[lane * 64 + d];
#pragma unroll
    for (int r = 0; r < 16; ++r) acc[r] += buf[(rg + r) * 64 + d] * wl;
  }
  __syncthreads();
#pragma unroll
  for (int r = 0; r < 16; ++r) buf[(rg + r) * 64 + lane] = acc[r];   // E
  __syncthreads();
  {
    int row = t >> 2, c0 = (t & 3) * 16;
    float v[16];
    float mx = -1e30f;
#pragma unroll
    for (int j = 0; j < 16; ++j) { v[j] = buf[row * 64 + c0 + j]; mx = fmaxf(mx, v[j]); }
    mx = fmaxf(mx, __shfl_xor(mx, 1));
    mx = fmaxf(mx, __shfl_xor(mx, 2));
    float s = 0.f;
#pragma unroll
    for (int j = 0; j < 16; ++j) { v[j] = __expf(v[j] - mx); s += v[j]; }
    s += __shfl_xor(s, 1);
    s += __shfl_xor(s, 2);
    float inv = 1.f / s;
#pragma unroll
    for (int j = 0; j < 16; ++j) buf[row * 64 + c0 + j] = v[j] * inv;  // attn
  }
  __syncthreads();
  float a2[16];
#pragma unroll
  for (int dd = 0; dd < 16; ++dd) a2[dd] = 0.f;
  for (int r = 0; r < 64; ++r) {
    float wv = w_bn[lane * 128 + r];
#pragma unroll
    for (int dd = 0; dd < 16; ++dd) a2[dd] += wv * buf[r * 64 + rg + dd];
  }
  float* mb = m1 + (size_t)b * 4096;
#pragma unroll
  for (int dd = 0; dd < 16; ++dd) mb[(rg + dd) * 64 + lane] = a2[dd];
}

// ---------------- K2: [cam | prep]; prep: q/k/vp via MFMA, zero-shuffle 8B stores,
// ot-pairs split across waves (2048 prep waves = 8 waves/CU) ----------------
__global__ __launch_bounds__(256) void prep_cam_kernel(const float* __restrict__ x,
                                                       const char* __restrict__ wall,
                                                       char* __restrict__ qd2,
                                                       char* __restrict__ kd2,
                                                       char* __restrict__ vpd2,
                                                       const float* __restrict__ Gp,
                                                       const float* __restrict__ w_cam,
                                                       const float* __restrict__ w_bn,
                                                       float* __restrict__ m1) {
  __shared__ float buf[4096];
  const int bxx = blockIdx.x;
  if (bxx < 8) {
    cam_body(Gp, w_cam, w_bn, m1, bxx, buf);
    return;
  }
  const int bx = bxx - 8;                 // 0..511
  const int t = threadIdx.x;
  const int w = t >> 6, l = t & 63, lo5 = l & 31, hi = l >> 5;
  const int chunk = bx * 2 + (w & 1);     // 0..1023
  const int p2 = w >> 1;                  // 0: {q,k}, 1: {v-lo, v-hi}
  const int b = chunk >> 7;
  const int c7 = chunk & 127;
  const int n0 = c7 * 32;
  const int tt = c7 >> 1;
  const int n = n0 + lo5;
  const float* xb = x + (size_t)b * C * HW;

  f32x16 fz;
#pragma unroll
  for (int r = 0; r < 16; ++r) fz[r] = 0.f;

  bf16x8 xf[4];
#pragma unroll
  for (int kc = 0; kc < 4; ++kc) {
    float xv[8];
#pragma unroll
    for (int j = 0; j < 8; ++j)
      xv[j] = xb[(size_t)(kc * 16 + hi * 8 + j) * HW + n];
    uint4 u;
    u.x = cvtpk(xv[0], xv[1]); u.y = cvtpk(xv[2], xv[3]);
    u.z = cvtpk(xv[4], xv[5]); u.w = cvtpk(xv[6], xv[7]);
    xf[kc] = __builtin_bit_cast(bf16x8, u);
  }

#pragma unroll
  for (int oo = 0; oo < 2; ++oo) {
    const int ot = p2 * 2 + oo;
    f32x16 acc = fz;
#pragma unroll
    for (int kc = 0; kc < 4; ++kc) {
      bf16x8 wf = *(const bf16x8*)(wall + ((ot << 2) | kc) * 1024 + l * 16);
      acc = (p2 == 0) ? mfma_bf16(wf, xf[kc], acc)   // D[col=n][row=out]
                      : mfma_bf16(xf[kc], wf, acc);  // D[col=c][row=m]
    }
    // lane(hi) owns rows 8e+4hi..8e+4hi+3 per octet e: one uint2, no shuffle
    char* base;
    int estride;
    if (ot == 0) {
      base = qd2 + ((size_t)b * HW + n) * 64 + hi * 8;
      estride = 16;
    } else if (ot == 1) {
      base = kd2 + ((size_t)(b * 64 + tt)) * 4096 + (c7 & 1) * 2048 + lo5 * 16 + hi * 8;
      estride = 512;
    } else {
      base = vpd2 + ((size_t)(b * 64 + tt)) * 8192 + (ot - 2) * 4096 +
             (c7 & 1) * 2048 + lo5 * 16 + hi * 8;
      estride = 512;
    }
    {
      uint2 u0, u1, u2, u3;
      u0.x = cvtpk(acc[0], acc[1]);   u0.y = cvtpk(acc[2], acc[3]);
      u1.x = cvtpk(acc[4], acc[5]);   u1.y = cvtpk(acc[6], acc[7]);
      u2.x = cvtpk(acc[8], acc[9]);   u2.y = cvtpk(acc[10], acc[11]);
      u3.x = cvtpk(acc[12], acc[13]); u3.y = cvtpk(acc[14], acc[15]);
      *(uint2*)(base) = u0;
      *(uint2*)(base + estride) = u1;
      *(uint2*)(base + 2 * estride) = u2;
      *(uint2*)(base + 3 * estride) = u3;
    }
  }
}

// ---------------- SAM flash attention: direct global->reg fragments, no LDS/barriers ----------------
__global__ __launch_bounds__(256) void fa_kernel(const char* __restrict__ qd2,
                                                 const char* __restrict__ kd2,
                                                 const char* __restrict__ vpd2,
                                                 char* __restrict__ op,
                                                 float* __restrict__ lp) {
  const int t = threadIdx.x;
  const int l = t & 63, lo5 = l & 31, hi = l >> 5;
  const int wv = t >> 6;
  const int bx = blockIdx.x;
  const int g = (bx & 7) | ((bx >> 8) << 3);   // XCD-aligned: group g lives on XCD g&7
  const int qt = (bx >> 3) & 31;
  const int b = g >> 2, kvs = g & 3;
  const int nq = qt * 128 + wv * 32 + lo5;

  const char* qb = qd2 + ((size_t)b * HW + nq) * 64;
  bf16x8 qf0 = *(const bf16x8*)(qb + hi * 16);
  bf16x8 qf1 = *(const bf16x8*)(qb + 32 + hi * 16);

  f32x16 fz;
#pragma unroll
  for (int r = 0; r < 16; ++r) fz[r] = 0.f;
  f32x16 o0 = fz, o1 = fz;
  float lrun = 0.f;

  const char* kbase = kd2 + ((size_t)(b * 64 + kvs * 16)) * 4096 + l * 16;
  const char* vbase = vpd2 + ((size_t)(b * 64 + kvs * 16)) * 8192 + l * 16;

  bf16x8 kf0 = *(const bf16x8*)(kbase);
  bf16x8 kf1 = *(const bf16x8*)(kbase + 1024);
  bf16x8 kf2 = *(const bf16x8*)(kbase + 2048);
  bf16x8 kf3 = *(const bf16x8*)(kbase + 3072);

#pragma unroll 1
  for (int i = 0; i < 16; ++i) {
    bf16x8 kn0, kn1, kn2, kn3;
    if (i < 15) {
      const char* kn = kbase + (size_t)(i + 1) * 4096;
      kn0 = *(const bf16x8*)(kn);
      kn1 = *(const bf16x8*)(kn + 1024);
      kn2 = *(const bf16x8*)(kn + 2048);
      kn3 = *(const bf16x8*)(kn + 3072);
    }
    const char* vb = vbase + (size_t)i * 8192;
    bf16x8 vfa[4], vfb[4];
#pragma unroll
    for (int ks = 0; ks < 4; ++ks) {
      vfa[ks] = *(const bf16x8*)(vb + ks * 1024);
      vfb[ks] = *(const bf16x8*)(vb + 4096 + ks * 1024);
    }
    f32x16 s0 = mfma_bf16(kf0, qf0, fz);
    s0 = mfma_bf16(kf1, qf1, s0);
    f32x16 s1 = mfma_bf16(kf2, qf0, fz);
    s1 = mfma_bf16(kf3, qf1, s1);
    float ps = 0.f;
#pragma unroll
    for (int r = 0; r < 16; ++r) {
      s0[r] = __builtin_amdgcn_exp2f(s0[r]);
      ps += s0[r];
    }
#pragma unroll
    for (int r = 0; r < 16; ++r) {
      s1[r] = __builtin_amdgcn_exp2f(s1[r]);
      ps += s1[r];
    }
    lrun += ps;                    // lane-local; cross-half merge once at end
#pragma unroll
    for (int ks = 0; ks < 4; ++ks) {
      const f32x16& pm = (ks < 2) ? s0 : s1;
      const int rb = (ks & 1) * 8;
      uint w0 = cvtpk(pm[rb + 0], pm[rb + 1]);
      uint w1 = cvtpk(pm[rb + 2], pm[rb + 3]);
      uint w2 = cvtpk(pm[rb + 4], pm[rb + 5]);
      uint w3 = cvtpk(pm[rb + 6], pm[rb + 7]);
      uint x0 = __shfl_xor(w0, 32);
      uint x1 = __shfl_xor(w1, 32);
      uint x2 = __shfl_xor(w2, 32);
      uint x3 = __shfl_xor(w3, 32);
      uint4 fw;
      fw.x = hi ? x2 : w0;
      fw.y = hi ? x3 : w1;
      fw.z = hi ? w2 : x0;
      fw.w = hi ? w3 : x1;
      bf16x8 pf = __builtin_bit_cast(bf16x8, fw);
      o0 = mfma_bf16(vfa[ks], pf, o0);
      o1 = mfma_bf16(vfb[ks], pf, o1);
    }
    kf0 = kn0; kf1 = kn1; kf2 = kn2; kf3 = kn3;
  }
  lrun += __shfl_xor(lrun, 32);

  ushort* opu = (ushort*)op;
  const size_t obase = ((size_t)(b * 64) * 4 + kvs) * HW + nq;
#pragma unroll
  for (int r = 0; r < 16; ++r) {
    int c0 = (r & 3) + 8 * (r >> 2) + 4 * hi;
    opu[obase + (size_t)c0 * 4 * HW] = bfb(o0[r]);
    opu[obase + (size_t)(c0 + 32) * 4 * HW] = bfb(o1[r]);
  }
  if (hi == 0) lp[(size_t)(kvs * 8 + b) * HW + nq] = lrun;
}

// ---------------- epilogue: out = x + M1@x + merge(op)/merge(l) ----------------
__global__ __launch_bounds__(256) void final_kernel(const float* __restrict__ x,
                                                    const float* __restrict__ m1,
                                                    const char* __restrict__ op,
                                                    const float* __restrict__ lp,
                                                    float* __restrict__ outp) {
  __shared__ __align__(16) float xt[4096];
  __shared__ __align__(16) float ms[4096];
  const int b = blockIdx.y, tt = blockIdx.x, t = threadIdx.x;
  const float4* xg = (const float4*)(x + (size_t)b * C * HW);
  float4* xt4 = (float4*)xt;
#pragma unroll
  for (int i = 0; i < 4; ++i) {
    int idx = t + i * 256;
    int c = idx >> 4, ng = idx & 15;
    xt4[c * 16 + (ng ^ (c & 15))] = xg[c * 1024 + tt * 16 + ng];
  }
  float4* ms4 = (float4*)ms;
  const float4* mg = (const float4*)(m1 + (size_t)b * 4096);
#pragma unroll
  for (int i = 0; i < 4; ++i) ms4[t + i * 256] = mg[t + i * 256];
  __syncthreads();
  const int n = t & 63, sub = t >> 6;
  const int gn = tt * 64 + n;
  float xr[64];
#pragma unroll
  for (int c = 0; c < 64; ++c)
    xr[c] = xt[c * 64 + (((n >> 2) ^ (c & 15)) << 2) + (n & 3)];
  float lsum = 0.f;
#pragma unroll
  for (int kvs = 0; kvs < 4; ++kvs) lsum += lp[(size_t)(kvs * 8 + b) * HW + gn];
  float linv = 1.f / lsum;
  const ushort* opu = (const ushort*)op;
  float acc[16];
#pragma unroll
  for (int ci = 0; ci < 16; ++ci) {
    int c = sub * 16 + ci;
    float osum = 0.f;
#pragma unroll
    for (int kvs = 0; kvs < 4; ++kvs) {
      ushort u = opu[((size_t)(b * 64 + c) * 4 + kvs) * HW + gn];
      osum += __builtin_bit_cast(float, (uint)u << 16);
    }
    acc[ci] = xr[c] + osum * linv;
  }
  for (int d = 0; d < 64; ++d) {
    float xv = xr[d];
    const float4* mr = (const float4*)(ms + d * 64 + sub * 16);
#pragma unroll
    for (int c4 = 0; c4 < 4; ++c4) {
      float4 mv = mr[c4];
      acc[c4 * 4 + 0] += mv.x * xv;
      acc[c4 * 4 + 1] += mv.y * xv;
      acc[c4 * 4 + 2] += mv.z * xv;
      acc[c4 * 4 + 3] += mv.w * xv;
    }
  }
  float* ob = outp + (size_t)b * C * HW + gn;
#pragma unroll
  for (int ci = 0; ci < 16; ++ci)
    ob[(size_t)(sub * 16 + ci) * HW] = acc[ci];
}

extern "C" void kernel_launch(void* const* d_in, const int* in_sizes, int n_in,
                              void* d_out, int out_size, void* d_ws, size_t ws_size,
                              hipStream_t stream) {
  const float* x     = (const float*)d_in[0];
  const float* w_cam = (const float*)d_in[1];
  const float* w_q   = (const float*)d_in[2];
  const float* w_k   = (const float*)d_in[3];
  const float* w_v   = (const float*)d_in[4];
  const float* w_bn  = (const float*)d_in[5];
  float* out = (float*)d_out;
  char* wsb = (char*)d_ws;

  // workspace layout (bytes) — total ~24.7 MB
  char*  wall = wsb;                               // 16 KB  wall fragments
  float* m1   = (float*)(wsb + 16384);             // 128 KB
  char*  qd2  = wsb + 147456;                      // 2 MB
  char*  kd2  = qd2 + 2097152;                     // 2 MB
  char*  vpd2 = kd2 + 2097152;                     // 4 MB
  float* lp   = (float*)(vpd2 + 4194304);          // 512 KB
  char*  op   = (char*)lp + 524288;                // 16 MB; Gp aliases first 1 MB
  float* Gp   = (float*)op;                        // 64 partials x 16 KB = 1 MB
  // alias safety: gram_fold writes Gp; prep_cam::cam reads Gp -> m1; fa then
  // overwrites the same bytes as op (stream-ordered after prep_cam); final reads op.

  gram_fold_kernel<<<68, 256, 0, stream>>>(x, Gp, w_bn, w_q, w_k, w_v, wall);
  prep_cam_kernel<<<520, 256, 0, stream>>>(x, wall, qd2, kd2, vpd2, Gp, w_cam, w_bn, m1);
  fa_kernel<<<1024, 256, 0, stream>>>(qd2, kd2, vpd2, op, lp);
  final_kernel<<<dim3(64, BB), 256, 0, stream>>>(x, m1, op, lp, out);
}

// Round 17
// 116.303 us; speedup vs baseline: 1.3849x; 1.0269x over previous
//
#include <hip/hip_runtime.h>

#define BB 8
#define C 64
#define HW 4096

typedef __attribute__((ext_vector_type(8))) __bf16 bf16x8;
typedef __attribute__((ext_vector_type(16))) float f32x16;
typedef unsigned int uint;
typedef unsigned short ushort;

__device__ __forceinline__ ushort bfb(float f) {
  return __builtin_bit_cast(ushort, (__bf16)f);
}
__device__ __forceinline__ uint pk2(float a, float b) {
  return (uint)bfb(a) | ((uint)bfb(b) << 16);
}
__device__ __forceinline__ uint cvtpk(float a, float b) {
  uint r;
  asm("v_cvt_pk_bf16_f32 %0, %1, %2" : "=v"(r) : "v"(a), "v"(b));
  return r;
}
__device__ __forceinline__ f32x16 mfma_bf16(bf16x8 a, bf16x8 b, f32x16 c) {
  return __builtin_amdgcn_mfma_f32_32x32x16_bf16(a, b, c, 0, 0, 0);
}

// ---------------- K1: [fold | gram] ----------------
__global__ __launch_bounds__(256) void gram_fold_kernel(const float* __restrict__ x,
                                                        float* __restrict__ Gp,
                                                        const float* __restrict__ w_bn,
                                                        const float* __restrict__ w_q,
                                                        const float* __restrict__ w_k,
                                                        const float* __restrict__ w_v,
                                                        char* __restrict__ wall) {
  __shared__ float slots[4][4096];   // 64 KB
  const int bxx = blockIdx.x;
  const int t = threadIdx.x;
  if (bxx < 4) {
    // ---- fold ----
    const int slot = bxx * 4 + (t >> 6);   // ot*4 + kc
    const int ot = slot >> 2, kc = slot & 3;
    const int l = t & 63, lo5 = l & 31, hi = l >> 5;
    float v[8];
    if (ot == 0) {
#pragma unroll
      for (int j = 0; j < 8; ++j)
        v[j] = 1.44269504088896f * w_q[lo5 * 64 + kc * 16 + hi * 8 + j];
    } else if (ot == 1) {
#pragma unroll
      for (int j = 0; j < 8; ++j) v[j] = w_k[lo5 * 64 + kc * 16 + hi * 8 + j];
    } else {
      int c = (ot - 2) * 32 + lo5;
#pragma unroll
      for (int j = 0; j < 8; ++j) {
        int d = kc * 16 + hi * 8 + j;
        float acc = 0.f;
        for (int e = 0; e < 64; ++e) acc += w_bn[c * 128 + 64 + e] * w_v[e * 64 + d];
        v[j] = acc;
      }
    }
    uint4 w;
    w.x = pk2(v[0], v[1]); w.y = pk2(v[2], v[3]);
    w.z = pk2(v[4], v[5]); w.w = pk2(v[6], v[7]);
    *(uint4*)(wall + slot * 1024 + l * 16) = w;
    return;
  }
  // ---- gram ----
  const int bx = bxx - 4;                 // 0..63
  const int b = bx >> 3, kb = bx & 7;
  const int w = t >> 6, l = t & 63, lo5 = l & 31, hi = l >> 5;
  const int k0 = kb * 512 + w * 128;
  const float* xb = x + (size_t)b * C * HW;
  f32x16 fz;
#pragma unroll
  for (int r = 0; r < 16; ++r) fz[r] = 0.f;
  f32x16 a00 = fz, a01 = fz, a10 = fz, a11 = fz;
#pragma unroll 1
  for (int kc = 0; kc < 8; ++kc) {
    int nb = k0 + kc * 16 + hi * 8;
    const float4* p0 = (const float4*)(xb + (size_t)lo5 * HW + nb);
    const float4* p1 = (const float4*)(xb + (size_t)(32 + lo5) * HW + nb);
    float v0[8], v1[8];
    {
      float4 a = p0[0], bq = p0[1];
      v0[0] = a.x; v0[1] = a.y; v0[2] = a.z; v0[3] = a.w;
      v0[4] = bq.x; v0[5] = bq.y; v0[6] = bq.z; v0[7] = bq.w;
      float4 c = p1[0], d = p1[1];
      v1[0] = c.x; v1[1] = c.y; v1[2] = c.z; v1[3] = c.w;
      v1[4] = d.x; v1[5] = d.y; v1[6] = d.z; v1[7] = d.w;
    }
    uint4 uh0, ul0, uh1, ul1;
    {
      float h[8], e[8];
#pragma unroll
      for (int j = 0; j < 8; ++j) { h[j] = (float)(__bf16)v0[j]; e[j] = v0[j] - h[j]; }
      uh0.x = pk2(h[0], h[1]); uh0.y = pk2(h[2], h[3]); uh0.z = pk2(h[4], h[5]); uh0.w = pk2(h[6], h[7]);
      ul0.x = cvtpk(e[0], e[1]); ul0.y = cvtpk(e[2], e[3]); ul0.z = cvtpk(e[4], e[5]); ul0.w = cvtpk(e[6], e[7]);
#pragma unroll
      for (int j = 0; j < 8; ++j) { h[j] = (float)(__bf16)v1[j]; e[j] = v1[j] - h[j]; }
      uh1.x = pk2(h[0], h[1]); uh1.y = pk2(h[2], h[3]); uh1.z = pk2(h[4], h[5]); uh1.w = pk2(h[6], h[7]);
      ul1.x = cvtpk(e[0], e[1]); ul1.y = cvtpk(e[2], e[3]); ul1.z = cvtpk(e[4], e[5]); ul1.w = cvtpk(e[6], e[7]);
    }
    bf16x8 f0h = __builtin_bit_cast(bf16x8, uh0);
    bf16x8 f0l = __builtin_bit_cast(bf16x8, ul0);
    bf16x8 f1h = __builtin_bit_cast(bf16x8, uh1);
    bf16x8 f1l = __builtin_bit_cast(bf16x8, ul1);
    a00 = mfma_bf16(f0h, f0h, a00); a00 = mfma_bf16(f0h, f0l, a00); a00 = mfma_bf16(f0l, f0h, a00);
    a01 = mfma_bf16(f0h, f1h, a01); a01 = mfma_bf16(f0h, f1l, a01); a01 = mfma_bf16(f0l, f1h, a01);
    a10 = mfma_bf16(f1h, f0h, a10); a10 = mfma_bf16(f1h, f0l, a10); a10 = mfma_bf16(f1l, f0h, a10);
    a11 = mfma_bf16(f1h, f1h, a11); a11 = mfma_bf16(f1h, f1l, a11); a11 = mfma_bf16(f1l, f1h, a11);
  }
#pragma unroll
  for (int r = 0; r < 16; ++r) {
    int row = (r & 3) + 8 * (r >> 2) + 4 * hi;
    slots[w][row * 64 + lo5] = a00[r];
    slots[w][row * 64 + 32 + lo5] = a01[r];
    slots[w][(32 + row) * 64 + lo5] = a10[r];
    slots[w][(32 + row) * 64 + 32 + lo5] = a11[r];
  }
  __syncthreads();
  float* g = Gp + (size_t)(b * 8 + kb) * 4096;
#pragma unroll
  for (int i = 0; i < 16; ++i) {
    int idx = t + i * 256;
    g[idx] = slots[0][idx] + slots[1][idx] + slots[2][idx] + slots[3][idx];
  }
}

// ---------------- cam body (256 threads, 16 KB LDS): reduce 8 partials, E, softmax, M1 ----------------
__device__ __forceinline__ void cam_body(const float* __restrict__ Gp,
                                         const float* __restrict__ w_cam,
                                         const float* __restrict__ w_bn,
                                         float* __restrict__ m1,
                                         int b, float* buf) {
  const int t = threadIdx.x;
#pragma unroll
  for (int i = 0; i < 16; ++i) {
    int idx = t + i * 256;
    float s = 0.f;
#pragma unroll
    for (int p = 0; p < 8; ++p)
      s += Gp[(size_t)(b * 8 + p) * 4096 + idx];
    buf[idx] = s;
  }
  __syncthreads();
  const int lane = t & 63, rg = (t >> 6) * 16;
  float acc[16];
#pragma unroll
  for (int r = 0; r < 16; ++r) acc[r] = 0.f;
  for (int c = 0; c < 64; ++c) {
    float g = buf[c * 64 + lane];
#pragma unroll
    for (int r = 0; r < 16; ++r) acc[r] += w_cam[(rg + r) * 64 + c] * g;
  }
  __syncthreads();
#pragma unroll
  for (int r = 0; r < 16; ++r) buf[(rg + r) * 64 + lane] = acc[r];   // T1
  __syncthreads();
#pragma unroll
  for (int r = 0; r < 16; ++r) acc[r] = 0.f;
  for (int d = 0; d < 64; ++d) {
    float wl = w_cam[lane * 64 + d];
#pragma unroll
    for (int r = 0; r < 16; ++r) acc[r] += buf[(rg + r) * 64 + d] * wl;
  }
  __syncthreads();
#pragma unroll
  for (int r = 0; r < 16; ++r) buf[(rg + r) * 64 + lane] = acc[r];   // E
  __syncthreads();
  {
    int row = t >> 2, c0 = (t & 3) * 16;
    float v[16];
    float mx = -1e30f;
#pragma unroll
    for (int j = 0; j < 16; ++j) { v[j] = buf[row * 64 + c0 + j]; mx = fmaxf(mx, v[j]); }
    mx = fmaxf(mx, __shfl_xor(mx, 1));
    mx = fmaxf(mx, __shfl_xor(mx, 2));
    float s = 0.f;
#pragma unroll
    for (int j = 0; j < 16; ++j) { v[j] = __expf(v[j] - mx); s += v[j]; }
    s += __shfl_xor(s, 1);
    s += __shfl_xor(s, 2);
    float inv = 1.f / s;
#pragma unroll
    for (int j = 0; j < 16; ++j) buf[row * 64 + c0 + j] = v[j] * inv;  // attn
  }
  __syncthreads();
  float a2[16];
#pragma unroll
  for (int dd = 0; dd < 16; ++dd) a2[dd] = 0.f;
  for (int r = 0; r < 64; ++r) {
    float wv = w_bn[lane * 128 + r];
#pragma unroll
    for (int dd = 0; dd < 16; ++dd) a2[dd] += wv * buf[r * 64 + rg + dd];
  }
  float* mb = m1 + (size_t)b * 4096;
#pragma unroll
  for (int dd = 0; dd < 16; ++dd) mb[(rg + dd) * 64 + lane] = a2[dd];
}

// ---------------- K2: [cam | prep]; prep: q/k/vp via MFMA, zero-shuffle 8B stores ----------------
__global__ __launch_bounds__(256) void prep_cam_kernel(const float* __restrict__ x,
                                                       const char* __restrict__ wall,
                                                       char* __restrict__ qd2,
                                                       char* __restrict__ kd2,
                                                       char* __restrict__ vpd2,
                                                       const float* __restrict__ Gp,
                                                       const float* __restrict__ w_cam,
                                                       const float* __restrict__ w_bn,
                                                       float* __restrict__ m1) {
  __shared__ float buf[4096];
  const int bxx = blockIdx.x;
  if (bxx < 8) {
    cam_body(Gp, w_cam, w_bn, m1, bxx, buf);
    return;
  }
  const int bx = bxx - 8;                 // 0..511
  const int t = threadIdx.x;
  const int w = t >> 6, l = t & 63, lo5 = l & 31, hi = l >> 5;
  const int chunk = bx * 2 + (w & 1);     // 0..1023
  const int p2 = w >> 1;                  // 0: {q,k}, 1: {v-lo, v-hi}
  const int b = chunk >> 7;
  const int c7 = chunk & 127;
  const int n0 = c7 * 32;
  const int tt = c7 >> 1;
  const int n = n0 + lo5;
  const float* xb = x + (size_t)b * C * HW;

  f32x16 fz;
#pragma unroll
  for (int r = 0; r < 16; ++r) fz[r] = 0.f;

  bf16x8 xf[4];
#pragma unroll
  for (int kc = 0; kc < 4; ++kc) {
    float xv[8];
#pragma unroll
    for (int j = 0; j < 8; ++j)
      xv[j] = xb[(size_t)(kc * 16 + hi * 8 + j) * HW + n];
    uint4 u;
    u.x = cvtpk(xv[0], xv[1]); u.y = cvtpk(xv[2], xv[3]);
    u.z = cvtpk(xv[4], xv[5]); u.w = cvtpk(xv[6], xv[7]);
    xf[kc] = __builtin_bit_cast(bf16x8, u);
  }

#pragma unroll
  for (int oo = 0; oo < 2; ++oo) {
    const int ot = p2 * 2 + oo;
    f32x16 acc = fz;
#pragma unroll
    for (int kc = 0; kc < 4; ++kc) {
      bf16x8 wf = *(const bf16x8*)(wall + ((ot << 2) | kc) * 1024 + l * 16);
      acc = (p2 == 0) ? mfma_bf16(wf, xf[kc], acc)   // D[col=n][row=out]
                      : mfma_bf16(xf[kc], wf, acc);  // D[col=c][row=m]
    }
    // lane(hi) owns rows 8e+4hi..8e+4hi+3 per octet e: one uint2, no shuffle
    char* base;
    int estride;
    if (ot == 0) {
      base = qd2 + ((size_t)b * HW + n) * 64 + hi * 8;
      estride = 16;
    } else if (ot == 1) {
      base = kd2 + ((size_t)(b * 64 + tt)) * 4096 + (c7 & 1) * 2048 + lo5 * 16 + hi * 8;
      estride = 512;
    } else {
      base = vpd2 + ((size_t)(b * 64 + tt)) * 8192 + (ot - 2) * 4096 +
             (c7 & 1) * 2048 + lo5 * 16 + hi * 8;
      estride = 512;
    }
    {
      uint2 u0, u1, u2, u3;
      u0.x = cvtpk(acc[0], acc[1]);   u0.y = cvtpk(acc[2], acc[3]);
      u1.x = cvtpk(acc[4], acc[5]);   u1.y = cvtpk(acc[6], acc[7]);
      u2.x = cvtpk(acc[8], acc[9]);   u2.y = cvtpk(acc[10], acc[11]);
      u3.x = cvtpk(acc[12], acc[13]); u3.y = cvtpk(acc[14], acc[15]);
      *(uint2*)(base) = u0;
      *(uint2*)(base + estride) = u1;
      *(uint2*)(base + 2 * estride) = u2;
      *(uint2*)(base + 3 * estride) = u3;
    }
  }
}

// ---------------- SAM flash attention: direct global->reg fragments; l via ones-row MFMA ----------------
__global__ __launch_bounds__(256) void fa_kernel(const char* __restrict__ qd2,
                                                 const char* __restrict__ kd2,
                                                 const char* __restrict__ vpd2,
                                                 char* __restrict__ op,
                                                 float* __restrict__ lp) {
  const int t = threadIdx.x;
  const int l = t & 63, lo5 = l & 31, hi = l >> 5;
  const int wv = t >> 6;
  const int bx = blockIdx.x;
  const int g = (bx & 7) | ((bx >> 8) << 3);   // XCD-aligned
  const int qt = (bx >> 3) & 31;
  const int b = g >> 2, kvs = g & 3;
  const int nq = qt * 128 + wv * 32 + lo5;

  const char* qb = qd2 + ((size_t)b * HW + nq) * 64;
  bf16x8 qf0 = *(const bf16x8*)(qb + hi * 16);
  bf16x8 qf1 = *(const bf16x8*)(qb + 32 + hi * 16);

  f32x16 fz;
#pragma unroll
  for (int r = 0; r < 16; ++r) fz[r] = 0.f;
  f32x16 o0 = fz, o1 = fz, lacc = fz;

  // ones A-fragment: A[row=lo5][k] = (lo5==0) ? 1.0 : 0  -> D row 0 = sum_k B[k][q]
  uint4 ow;
  {
    uint ob = (lo5 == 0) ? 0x3F803F80u : 0u;
    ow.x = ob; ow.y = ob; ow.z = ob; ow.w = ob;
  }
  const bf16x8 onesf = __builtin_bit_cast(bf16x8, ow);

  const char* kbase = kd2 + ((size_t)(b * 64 + kvs * 16)) * 4096 + l * 16;
  const char* vbase = vpd2 + ((size_t)(b * 64 + kvs * 16)) * 8192 + l * 16;

  bf16x8 kf0 = *(const bf16x8*)(kbase);
  bf16x8 kf1 = *(const bf16x8*)(kbase + 1024);
  bf16x8 kf2 = *(const bf16x8*)(kbase + 2048);
  bf16x8 kf3 = *(const bf16x8*)(kbase + 3072);

#pragma unroll 1
  for (int i = 0; i < 16; ++i) {
    bf16x8 kn0, kn1, kn2, kn3;
    if (i < 15) {
      const char* kn = kbase + (size_t)(i + 1) * 4096;
      kn0 = *(const bf16x8*)(kn);
      kn1 = *(const bf16x8*)(kn + 1024);
      kn2 = *(const bf16x8*)(kn + 2048);
      kn3 = *(const bf16x8*)(kn + 3072);
    }
    const char* vb = vbase + (size_t)i * 8192;
    bf16x8 vfa[4], vfb[4];
#pragma unroll
    for (int ks = 0; ks < 4; ++ks) {
      vfa[ks] = *(const bf16x8*)(vb + ks * 1024);
      vfb[ks] = *(const bf16x8*)(vb + 4096 + ks * 1024);
    }
    f32x16 s0 = mfma_bf16(kf0, qf0, fz);
    s0 = mfma_bf16(kf1, qf1, s0);
    f32x16 s1 = mfma_bf16(kf2, qf0, fz);
    s1 = mfma_bf16(kf3, qf1, s1);
#pragma unroll
    for (int r = 0; r < 16; ++r) s0[r] = __builtin_amdgcn_exp2f(s0[r]);
#pragma unroll
    for (int r = 0; r < 16; ++r) s1[r] = __builtin_amdgcn_exp2f(s1[r]);
#pragma unroll
    for (int ks = 0; ks < 4; ++ks) {
      const f32x16& pm = (ks < 2) ? s0 : s1;
      const int rb = (ks & 1) * 8;
      uint w0 = cvtpk(pm[rb + 0], pm[rb + 1]);
      uint w1 = cvtpk(pm[rb + 2], pm[rb + 3]);
      uint w2 = cvtpk(pm[rb + 4], pm[rb + 5]);
      uint w3 = cvtpk(pm[rb + 6], pm[rb + 7]);
      uint x0 = __shfl_xor(w0, 32);
      uint x1 = __shfl_xor(w1, 32);
      uint x2 = __shfl_xor(w2, 32);
      uint x3 = __shfl_xor(w3, 32);
      uint4 fw;
      fw.x = hi ? x2 : w0;
      fw.y = hi ? x3 : w1;
      fw.z = hi ? w2 : x0;
      fw.w = hi ? w3 : x1;
      bf16x8 pf = __builtin_bit_cast(bf16x8, fw);
      o0 = mfma_bf16(vfa[ks], pf, o0);
      o1 = mfma_bf16(vfb[ks], pf, o1);
      lacc = mfma_bf16(onesf, pf, lacc);   // row 0 accumulates sum_m P[m][q]
    }
    kf0 = kn0; kf1 = kn1; kf2 = kn2; kf3 = kn3;
  }

  ushort* opu = (ushort*)op;
  const size_t obase = ((size_t)(b * 64) * 4 + kvs) * HW + nq;
#pragma unroll
  for (int r = 0; r < 16; ++r) {
    int c0 = (r & 3) + 8 * (r >> 2) + 4 * hi;
    opu[obase + (size_t)c0 * 4 * HW] = bfb(o0[r]);
    opu[obase + (size_t)(c0 + 32) * 4 * HW] = bfb(o1[r]);
  }
  if (hi == 0) lp[(size_t)(kvs * 8 + b) * HW + nq] = lacc[0];
}

// ---------------- epilogue: out = x + M1@x + merge(op)/merge(l) ----------------
__global__ __launch_bounds__(256) void final_kernel(const float* __restrict__ x,
                                                    const float* __restrict__ m1,
                                                    const char* __restrict__ op,
                                                    const float* __restrict__ lp,
                                                    float* __restrict__ outp) {
  __shared__ __align__(16) float xt[4096];
  __shared__ __align__(16) float ms[4096];
  const int b = blockIdx.y, tt = blockIdx.x, t = threadIdx.x;
  const float4* xg = (const float4*)(x + (size_t)b * C * HW);
  float4* xt4 = (float4*)xt;
#pragma unroll
  for (int i = 0; i < 4; ++i) {
    int idx = t + i * 256;
    int c = idx >> 4, ng = idx & 15;
    xt4[c * 16 + (ng ^ (c & 15))] = xg[c * 1024 + tt * 16 + ng];
  }
  float4* ms4 = (float4*)ms;
  const float4* mg = (const float4*)(m1 + (size_t)b * 4096);
#pragma unroll
  for (int i = 0; i < 4; ++i) ms4[t + i * 256] = mg[t + i * 256];
  __syncthreads();
  const int n = t & 63, sub = t >> 6;
  const int gn = tt * 64 + n;
  float xr[64];
#pragma unroll
  for (int c = 0; c < 64; ++c)
    xr[c] = xt[c * 64 + (((n >> 2) ^ (c & 15)) << 2) + (n & 3)];
  float lsum = 0.f;
#pragma unroll
  for (int kvs = 0; kvs < 4; ++kvs) lsum += lp[(size_t)(kvs * 8 + b) * HW + gn];
  float linv = 1.f / lsum;
  const ushort* opu = (const ushort*)op;
  float acc[16];
#pragma unroll
  for (int ci = 0; ci < 16; ++ci) {
    int c = sub * 16 + ci;
    float osum = 0.f;
#pragma unroll
    for (int kvs = 0; kvs < 4; ++kvs) {
      ushort u = opu[((size_t)(b * 64 + c) * 4 + kvs) * HW + gn];
      osum += __builtin_bit_cast(float, (uint)u << 16);
    }
    acc[ci] = xr[c] + osum * linv;
  }
  for (int d = 0; d < 64; ++d) {
    float xv = xr[d];
    const float4* mr = (const float4*)(ms + d * 64 + sub * 16);
#pragma unroll
    for (int c4 = 0; c4 < 4; ++c4) {
      float4 mv = mr[c4];
      acc[c4 * 4 + 0] += mv.x * xv;
      acc[c4 * 4 + 1] += mv.y * xv;
      acc[c4 * 4 + 2] += mv.z * xv;
      acc[c4 * 4 + 3] += mv.w * xv;
    }
  }
  float* ob = outp + (size_t)b * C * HW + gn;
#pragma unroll
  for (int ci = 0; ci < 16; ++ci)
    ob[(size_t)(sub * 16 + ci) * HW] = acc[ci];
}

extern "C" void kernel_launch(void* const* d_in, const int* in_sizes, int n_in,
                              void* d_out, int out_size, void* d_ws, size_t ws_size,
                              hipStream_t stream) {
  const float* x     = (const float*)d_in[0];
  const float* w_cam = (const float*)d_in[1];
  const float* w_q   = (const float*)d_in[2];
  const float* w_k   = (const float*)d_in[3];
  const float* w_v   = (const float*)d_in[4];
  const float* w_bn  = (const float*)d_in[5];
  float* out = (float*)d_out;
  char* wsb = (char*)d_ws;

  // workspace layout (bytes) — total ~24.7 MB
  char*  wall = wsb;                               // 16 KB  wall fragments
  float* m1   = (float*)(wsb + 16384);             // 128 KB
  char*  qd2  = wsb + 147456;                      // 2 MB
  char*  kd2  = qd2 + 2097152;                     // 2 MB
  char*  vpd2 = kd2 + 2097152;                     // 4 MB
  float* lp   = (float*)(vpd2 + 4194304);          // 512 KB
  char*  op   = (char*)lp + 524288;                // 16 MB; Gp aliases first 1 MB
  float* Gp   = (float*)op;                        // 64 partials x 16 KB = 1 MB

  gram_fold_kernel<<<68, 256, 0, stream>>>(x, Gp, w_bn, w_q, w_k, w_v, wall);
  prep_cam_kernel<<<520, 256, 0, stream>>>(x, wall, qd2, kd2, vpd2, Gp, w_cam, w_bn, m1);
  fa_kernel<<<1024, 256, 0, stream>>>(qd2, kd2, vpd2, op, lp);
  final_kernel<<<dim3(64, BB), 256, 0, stream>>>(x, m1, op, lp, out);
}